// Round 10
// baseline (488.321 us; speedup 1.0000x reference)
//
#include <hip/hip_runtime.h>
#include <hip/hip_bf16.h>
#include <math.h>
#include <stdint.h>

#define NN 50000
#define NE 500000
#define DIN 264
#define KP1 288      // DIN padded to multiple of 32
#define HID 128
#define EDIM 16

typedef __attribute__((ext_vector_type(8))) short short8;
typedef __attribute__((ext_vector_type(4))) float f32x4;

__device__ __forceinline__ short f2bf(float v) {
    union { float f; unsigned u; } x; x.f = v;
    unsigned r = x.u + 0x7fff + ((x.u >> 16) & 1);
    return (short)(r >> 16);
}
__device__ __forceinline__ float bf2f(short v) {
    union { float f; unsigned u; } x;
    x.u = ((unsigned)(unsigned short)v) << 16;
    return x.f;
}
// unpack two bf16 packed in a dword
__device__ __forceinline__ float bflo(unsigned u) {
    union { float f; unsigned u; } x; x.u = u << 16; return x.f;
}
__device__ __forceinline__ float bfhi(unsigned u) {
    union { float f; unsigned u; } x; x.u = u & 0xffff0000u; return x.f;
}

__device__ __forceinline__ void gload_lds16(const void* g, void* l) {
    __builtin_amdgcn_global_load_lds(
        (const __attribute__((address_space(1))) unsigned int*)g,
        (__attribute__((address_space(3))) unsigned int*)l, 16, 0, 0);
}

// ---------------- CSR build (dst -> in-edges) ----------------
__global__ void k_count(const int* __restrict__ dst, int* __restrict__ cnt) {
    int e = blockIdx.x * blockDim.x + threadIdx.x;
    if (e < NE) atomicAdd(&cnt[dst[e]], 1);
}

__global__ __launch_bounds__(256) void k_scan1(const int* __restrict__ cnt,
                                               int* __restrict__ off, int* __restrict__ bsum) {
    __shared__ int buf[256];
    int b = blockIdx.x, t = threadIdx.x;
    int i = b * 256 + t;
    int v = (i < NN) ? cnt[i] : 0;
    buf[t] = v; __syncthreads();
    for (int s = 1; s < 256; s <<= 1) {
        int u = (t >= s) ? buf[t - s] : 0; __syncthreads();
        buf[t] += u; __syncthreads();
    }
    if (i < NN) off[i + 1] = buf[t];
    if (t == 255) bsum[b] = buf[255];
}

__global__ void k_scan2(int* __restrict__ bsum, int nb) {
    __shared__ int buf[256];
    int t = threadIdx.x;
    int o = (t < nb) ? bsum[t] : 0;
    buf[t] = o; __syncthreads();
    for (int s = 1; s < 256; s <<= 1) {
        int u = (t >= s) ? buf[t - s] : 0; __syncthreads();
        buf[t] += u; __syncthreads();
    }
    if (t < nb) bsum[t] = buf[t] - o;   // exclusive
}

// finalize offsets AND copy to cur in one pass
__global__ void k_scan3c(int* __restrict__ off, const int* __restrict__ bsum,
                         int* __restrict__ cur) {
    int j = blockIdx.x * 256 + threadIdx.x;   // 0..NN
    if (j > NN) return;
    int v = (j == 0) ? 0 : off[j] + bsum[(j - 1) >> 8];
    off[j] = v;
    if (j < NN) cur[j] = v;
}

// ONE 8B scattered write per edge (1 dirty line, vs 3 for split arrays)
__global__ void k_scatter(const int* __restrict__ src, const int* __restrict__ dst,
                          int* __restrict__ cur, int2* __restrict__ csr_se) {
    int e = blockIdx.x * blockDim.x + threadIdx.x;
    if (e < NE) {
        int d = dst[e];
        int p = atomicAdd(&cur[d], 1);
        csr_se[p] = make_int2(src[e], e);
    }
}

// dstp is constant per CSR segment -> fill CONTIGUOUSLY from off (no scatter)
__global__ void k_fill_dst(const int* __restrict__ off, int* __restrict__ dstp) {
    int i = blockIdx.x * 256 + threadIdx.x;
    if (i < NN) {
        int b0 = off[i], b1 = off[i + 1];
        for (int p = b0; p < b1; ++p) dstp[p] = i;
    }
}

// ---------------- weight/bias/input prep ----------------
__global__ void k_cvt_x(const float* __restrict__ x, short* __restrict__ xb) {
    int idx = blockIdx.x * 256 + threadIdx.x;
    if (idx >= NN * KP1) return;
    int i = idx / KP1, k = idx - i * KP1;
    xb[idx] = (k < DIN) ? f2bf(x[(size_t)i * DIN + k]) : (short)0;
}

// all weight transposes + bias concats + att block-diag expansion in ONE dispatch
__global__ void k_prep_w(const float* __restrict__ Wl1, const float* __restrict__ Wr1,
                         const float* __restrict__ Wres, const float* __restrict__ Wl2,
                         const float* __restrict__ Wr2, const float* __restrict__ Wout,
                         const float* __restrict__ bl1, const float* __restrict__ br1,
                         const float* __restrict__ bres, const float* __restrict__ bl2,
                         const float* __restrict__ br2,
                         const float* __restrict__ We1, const float* __restrict__ We2,
                         const float* __restrict__ att1, const float* __restrict__ att2,
                         short* __restrict__ Wt1, short* __restrict__ Wt2,
                         short* __restrict__ Wt3, float* __restrict__ bcat1,
                         float* __restrict__ bcat2,
                         short* __restrict__ WeT1, short* __restrict__ WeT2,
                         short* __restrict__ attB1, short* __restrict__ attB2) {
    int idx = blockIdx.x * 256 + threadIdx.x;
    if (idx < 384 * KP1) {
        int n = idx / KP1, k = idx - n * KP1;
        float v = 0.f;
        if (k < DIN) {
            const float* W = (n < 128) ? Wl1 : ((n < 256) ? Wr1 : Wres);
            v = W[(size_t)k * 128 + (n & 127)];
        }
        Wt1[idx] = f2bf(v);
        return;
    }
    idx -= 384 * KP1;
    if (idx < 256 * 128) {
        int n = idx >> 7, k = idx & 127;
        const float* W = (n < 128) ? Wl2 : Wr2;
        Wt2[idx] = f2bf(W[(size_t)k * 128 + (n & 127)]);
        return;
    }
    idx -= 256 * 128;
    if (idx < 128 * 128) {
        int n = idx >> 7, k = idx & 127;
        Wt3[idx] = f2bf(Wout[(size_t)k * 128 + n]);
        return;
    }
    idx -= 128 * 128;
    if (idx < 384) {
        bcat1[idx] = (idx < 128) ? bl1[idx] : ((idx < 256) ? br1[idx - 128] : bres[idx - 256]);
        return;
    }
    idx -= 384;
    if (idx < 256) {
        bcat2[idx] = (idx < 128) ? bl2[idx] : br2[idx - 128];
        return;
    }
    idx -= 256;
    if (idx < 128 * 32) {
        int n = idx >> 5, k = idx & 31;
        WeT1[idx] = (k < EDIM) ? f2bf(We1[(size_t)k * 128 + n]) : (short)0;
        return;
    }
    idx -= 128 * 32;
    if (idx < 128 * 32) {
        int n = idx >> 5, k = idx & 31;
        WeT2[idx] = (k < EDIM) ? f2bf(We2[(size_t)k * 128 + n]) : (short)0;
        return;
    }
    idx -= 128 * 32;
    if (idx < 16 * 128) {
        int n = idx >> 7, k = idx & 127;
        attB1[idx] = (n == (k >> 5)) ? f2bf(att1[k]) : (short)0;
        return;
    }
    idx -= 16 * 128;
    if (idx < 16 * 128) {
        int n = idx >> 7, k = idx & 127;
        attB2[idx] = (n == (k >> 5)) ? f2bf(att2[k]) : (short)0;
    }
}

// ---------------- bf16 MFMA GEMM: C[M x NS] = A[M x Kpad] @ Bt[NS x Kpad]^T + bias ----------------
template <bool BF16OUT>
__global__ __launch_bounds__(256) void k_mfma_gemm(const short* __restrict__ A,
                                                   const short* __restrict__ Bt,
                                                   const float* __restrict__ bias,
                                                   float* __restrict__ Cf,
                                                   short* __restrict__ Cb,
                                                   int M, int Kpad, int NS) {
    __shared__ short As[128 * 32];
    __shared__ short Bs[128 * 32];
    int t = threadIdx.x;
    int lane = t & 63, wid = t >> 6;
    int wm = (wid & 1) * 64, wn = (wid >> 1) * 64;
    int cl = lane & 15, quad = lane >> 4;
    int row0 = blockIdx.x * 128;
    int col0 = blockIdx.y * 128;

    f32x4 acc[4][4];
#pragma unroll
    for (int i = 0; i < 4; ++i)
#pragma unroll
        for (int j = 0; j < 4; ++j) acc[i][j] = (f32x4)0.f;

    for (int k0 = 0; k0 < Kpad; k0 += 32) {
#pragma unroll
        for (int r = 0; r < 2; ++r) {
            int c = t + r * 256;                     // chunk 0..511
            int m = c >> 2;
            int row = row0 + m; if (row >= M) row = M - 1;
            const char* ga = (const char*)A + ((size_t)row * Kpad + k0) * 2 + (c & 3) * 16;
            gload_lds16(ga, (char*)As + c * 16);
            int n = col0 + m;
            const char* gb = (const char*)Bt + ((size_t)n * Kpad + k0) * 2 + (c & 3) * 16;
            gload_lds16(gb, (char*)Bs + c * 16);
        }
        __syncthreads();

        short8 a[4], b[4];
#pragma unroll
        for (int mi = 0; mi < 4; ++mi)
            a[mi] = *(const short8*)&As[(wm + mi * 16 + cl) * 32 + quad * 8];
#pragma unroll
        for (int ni = 0; ni < 4; ++ni)
            b[ni] = *(const short8*)&Bs[(wn + ni * 16 + cl) * 32 + quad * 8];
#pragma unroll
        for (int mi = 0; mi < 4; ++mi)
#pragma unroll
            for (int ni = 0; ni < 4; ++ni)
                acc[mi][ni] = __builtin_amdgcn_mfma_f32_16x16x32_bf16(a[mi], b[ni], acc[mi][ni], 0, 0, 0);
        __syncthreads();
    }

#pragma unroll
    for (int mi = 0; mi < 4; ++mi)
#pragma unroll
        for (int ni = 0; ni < 4; ++ni) {
            int col = col0 + wn + ni * 16 + cl;
            float bv = bias[col];
#pragma unroll
            for (int r = 0; r < 4; ++r) {
                int row = row0 + wm + mi * 16 + quad * 4 + r;
                if (row < M) {
                    float v = acc[mi][ni][r] + bv;
                    if (BF16OUT) Cb[(size_t)row * NS + col] = f2bf(v);
                    else         Cf[(size_t)row * NS + col] = v;
                }
            }
        }
}

// ---------------- GEMM (M x 128 @ 128x128) with fused LayerNorm epilogue ----------------
__global__ __launch_bounds__(256) void k_gemm_ln(const short* __restrict__ A,
                                                 const short* __restrict__ Bt,
                                                 const float* __restrict__ bias,
                                                 const float* __restrict__ gamma,
                                                 const float* __restrict__ beta,
                                                 float* __restrict__ out, int M) {
    __shared__ short As[128 * 32];
    __shared__ short Bs[128 * 32];
    __shared__ float redS[128][2];
    int t = threadIdx.x;
    int lane = t & 63, wid = t >> 6;
    int wm = (wid & 1) * 64, wn = (wid >> 1) * 64;
    int cl = lane & 15, quad = lane >> 4;
    int row0 = blockIdx.x * 128;
    int wh = wid >> 1;                 // which 64-col half this wave owns

    f32x4 acc[4][4];
#pragma unroll
    for (int i = 0; i < 4; ++i)
#pragma unroll
        for (int j = 0; j < 4; ++j) acc[i][j] = (f32x4)0.f;

    for (int k0 = 0; k0 < 128; k0 += 32) {
#pragma unroll
        for (int r = 0; r < 2; ++r) {
            int c = t + r * 256;
            int m = c >> 2;
            int row = row0 + m; if (row >= M) row = M - 1;
            const char* ga = (const char*)A + ((size_t)row * 128 + k0) * 2 + (c & 3) * 16;
            gload_lds16(ga, (char*)As + c * 16);
            const char* gb = (const char*)Bt + ((size_t)m * 128 + k0) * 2 + (c & 3) * 16;
            gload_lds16(gb, (char*)Bs + c * 16);
        }
        __syncthreads();

        short8 a[4], b[4];
#pragma unroll
        for (int mi = 0; mi < 4; ++mi)
            a[mi] = *(const short8*)&As[(wm + mi * 16 + cl) * 32 + quad * 8];
#pragma unroll
        for (int ni = 0; ni < 4; ++ni)
            b[ni] = *(const short8*)&Bs[(wn + ni * 16 + cl) * 32 + quad * 8];
#pragma unroll
        for (int mi = 0; mi < 4; ++mi)
#pragma unroll
            for (int ni = 0; ni < 4; ++ni)
                acc[mi][ni] = __builtin_amdgcn_mfma_f32_16x16x32_bf16(a[mi], b[ni], acc[mi][ni], 0, 0, 0);
        __syncthreads();
    }

    // per-column params for this thread's 4 column slots
    float bv[4], gv[4], bev[4];
#pragma unroll
    for (int ni = 0; ni < 4; ++ni) {
        int col = wn + ni * 16 + cl;
        bv[ni] = bias[col]; gv[ni] = gamma[col]; bev[ni] = beta[col];
    }

    // ---- row sums (over this wave's 64 cols) ----
    float s[4][4];
#pragma unroll
    for (int mi = 0; mi < 4; ++mi)
#pragma unroll
        for (int r = 0; r < 4; ++r) {
            float v = (acc[mi][0][r] + bv[0]) + (acc[mi][1][r] + bv[1]) +
                      (acc[mi][2][r] + bv[2]) + (acc[mi][3][r] + bv[3]);
            v += __shfl_xor(v, 1, 64);
            v += __shfl_xor(v, 2, 64);
            v += __shfl_xor(v, 4, 64);
            v += __shfl_xor(v, 8, 64);
            s[mi][r] = v;
        }
    if (cl == 0) {
#pragma unroll
        for (int mi = 0; mi < 4; ++mi)
#pragma unroll
            for (int r = 0; r < 4; ++r)
                redS[wm + mi * 16 + quad * 4 + r][wh] = s[mi][r];
    }
    __syncthreads();
    float mean[4][4];
#pragma unroll
    for (int mi = 0; mi < 4; ++mi)
#pragma unroll
        for (int r = 0; r < 4; ++r) {
            int rl = wm + mi * 16 + quad * 4 + r;
            mean[mi][r] = (redS[rl][0] + redS[rl][1]) * (1.f / 128.f);
        }
    __syncthreads();

    // ---- row variances ----
#pragma unroll
    for (int mi = 0; mi < 4; ++mi)
#pragma unroll
        for (int r = 0; r < 4; ++r) {
            float q = 0.f;
#pragma unroll
            for (int ni = 0; ni < 4; ++ni) {
                float d = acc[mi][ni][r] + bv[ni] - mean[mi][r];
                q = fmaf(d, d, q);
            }
            q += __shfl_xor(q, 1, 64);
            q += __shfl_xor(q, 2, 64);
            q += __shfl_xor(q, 4, 64);
            q += __shfl_xor(q, 8, 64);
            s[mi][r] = q;
        }
    if (cl == 0) {
#pragma unroll
        for (int mi = 0; mi < 4; ++mi)
#pragma unroll
            for (int r = 0; r < 4; ++r)
                redS[wm + mi * 16 + quad * 4 + r][wh] = s[mi][r];
    }
    __syncthreads();

#pragma unroll
    for (int mi = 0; mi < 4; ++mi)
#pragma unroll
        for (int r = 0; r < 4; ++r) {
            int rl = wm + mi * 16 + quad * 4 + r;
            int row = row0 + rl;
            if (row < M) {
                float rstd = rsqrtf((redS[rl][0] + redS[rl][1]) * (1.f / 128.f) + 1e-5f);
#pragma unroll
                for (int ni = 0; ni < 4; ++ni) {
                    int col = wn + ni * 16 + cl;
                    float d = acc[mi][ni][r] + bv[ni] - mean[mi][r];
                    out[(size_t)row * 128 + col] = fmaf(d * rstd, gv[ni], bev[ni]);
                }
            }
        }
}

// ---------------- edge score kernel (v4: direct-ea read, no eaperm) ----------------
// Per block: 128 CSR-ordered edges, 8 waves.
// Phase 1: ee[128x128] = ea_rows @ WeT^T via MFMA; A-fragments read DIRECTLY
//          from f32 ea via csr_se[pos].y with in-register bf16 convert
//          (k=16..31 is zero padding -> quads 2,3 contribute zero, skip loads).
// Phase 2: g = leaky(ee + xl[src] + xr[dst]) -> Gs (lane=f: coalesced row reads).
// Phase 3: S[128x16] = g @ attB^T (attB block-diag; Ab/Gs stride 136).
// Phase 4: pe[e,h] = exp(S).
template <int STRIDE>
__global__ __launch_bounds__(512) void k_edge_score(const int2* __restrict__ csr_se,
                                                    const int* __restrict__ dstp,
                                                    const float* __restrict__ ea,
                                                    const short* __restrict__ WeT,
                                                    const short* __restrict__ attB,
                                                    const short* __restrict__ C,
                                                    float* __restrict__ pe) {
    __shared__ short Gs[128 * 136];
    __shared__ short Ab[16 * 136];
    __shared__ int sS[128], sD[128];
    int t = threadIdx.x;
    int lane = t & 63, wid = t >> 6;          // 8 waves
    int wm2 = (wid & 1) * 64;                 // edge half
    int wn2 = (wid >> 1) * 32;                // f quarter
    int cl = lane & 15, quad = lane >> 4;
    long e0 = (long)blockIdx.x * 128;

    if (t < 128) {
        long ep = e0 + t; if (ep >= NE) ep = NE - 1;
        sS[t] = csr_se[ep].x;
        sD[t] = dstp[ep];
    } else if (t < 384) {
        int u = t - 128;                      // 0..255 -> 16 rows x 16 chunks of 8 shorts
        int rr = u >> 4, cc = (u & 15) * 8;
        *(short8*)&Ab[rr * 136 + cc] = *(const short8*)&attB[rr * 128 + cc];
    }

    // ---- phase 1: A-frags direct from f32 ea (quads 0,1 only; 2,3 are k-pad zeros) ----
    short8 a[4], b[2];
#pragma unroll
    for (int mi = 0; mi < 4; ++mi) {
        long e = e0 + wm2 + mi * 16 + cl; if (e >= NE) e = NE - 1;
        if (quad < 2) {
            int eid = csr_se[e].y;
            const float4* r = (const float4*)(ea + (size_t)eid * EDIM + quad * 8);
            float4 v0 = r[0], v1 = r[1];
            short8 av;
            av[0] = f2bf(v0.x); av[1] = f2bf(v0.y); av[2] = f2bf(v0.z); av[3] = f2bf(v0.w);
            av[4] = f2bf(v1.x); av[5] = f2bf(v1.y); av[6] = f2bf(v1.z); av[7] = f2bf(v1.w);
            a[mi] = av;
        } else {
            a[mi] = (short8)0;
        }
    }
#pragma unroll
    for (int ni = 0; ni < 2; ++ni)
        b[ni] = *(const short8*)&WeT[(size_t)(wn2 + ni * 16 + cl) * 32 + quad * 8];

    f32x4 acc[4][2];
#pragma unroll
    for (int i = 0; i < 4; ++i) { acc[i][0] = (f32x4)0.f; acc[i][1] = (f32x4)0.f; }
#pragma unroll
    for (int mi = 0; mi < 4; ++mi)
#pragma unroll
        for (int ni = 0; ni < 2; ++ni)
            acc[mi][ni] = __builtin_amdgcn_mfma_f32_16x16x32_bf16(a[mi], b[ni], acc[mi][ni], 0, 0, 0);
    __syncthreads();   // sS/sD/Ab ready

    // ---- phase 2: g = leaky(ee + xl + xr) -> Gs (coalesced: lanes = consecutive f) ----
#pragma unroll
    for (int mi = 0; mi < 4; ++mi) {
#pragma unroll
        for (int r = 0; r < 4; ++r) {
            int eloc = wm2 + mi * 16 + quad * 4 + r;
            const short* xlr = C + (size_t)sS[eloc] * STRIDE;
            const short* xrr = C + (size_t)sD[eloc] * STRIDE + 128;
            int f0 = wn2 + cl, f1 = wn2 + 16 + cl;
            float xl0 = bf2f(xlr[f0]), xr0 = bf2f(xrr[f0]);
            float xl1 = bf2f(xlr[f1]), xr1 = bf2f(xrr[f1]);
            float g0 = acc[mi][0][r] + xl0 + xr0;
            float g1 = acc[mi][1][r] + xl1 + xr1;
            g0 = fmaxf(g0, 0.2f * g0);
            g1 = fmaxf(g1, 0.2f * g1);
            Gs[eloc * 136 + f0] = f2bf(g0);
            Gs[eloc * 136 + f1] = f2bf(g1);
        }
    }
    __syncthreads();

    // ---- phase 3: scores = g @ attB^T (16 edges per wave, 4 MFMAs) ----
    f32x4 sacc = (f32x4)0.f;
    int em0 = wid * 16;
#pragma unroll
    for (int ks = 0; ks < 4; ++ks) {
        short8 ag = *(const short8*)&Gs[(em0 + cl) * 136 + ks * 32 + quad * 8];
        short8 bg = *(const short8*)&Ab[cl * 136 + ks * 32 + quad * 8];
        sacc = __builtin_amdgcn_mfma_f32_16x16x32_bf16(ag, bg, sacc, 0, 0, 0);
    }

    // ---- phase 4: exp + store (D layout: col=cl (head), row=quad*4+r (edge)) ----
    if (cl < 4) {
#pragma unroll
        for (int r = 0; r < 4; ++r) {
            long epos = e0 + em0 + quad * 4 + r;
            if (epos < NE) pe[epos * 4 + cl] = __expf(sacc[r]);
        }
    }
}

// ---------------- slim softmax-aggregate + epilogue ----------------
// ONE WAVE PER 4-NODE CHUNK. Per edge: csr_se + pe (per-head broadcast) + xl dword
// + 3 FMAs. No shfl, no exp (scores precomputed by k_edge_score). l_run needs no
// reduce: pe is uniform across each 16-lane head group. Two accumulator sets
// break the serial FMA chain; next-pair prefetch hides gather latency.
template <int STRIDE>
__global__ __launch_bounds__(256) void k_fused_agg(const int* __restrict__ off,
                                                   const int2* __restrict__ csr_se,
                                                   const float* __restrict__ pe,
                                                   const short* __restrict__ C,
                                                   const short* __restrict__ resid, int rstride,
                                                   const float* __restrict__ bias,
                                                   const float* __restrict__ gamma,
                                                   const float* __restrict__ beta,
                                                   short* __restrict__ outb) {
    int t = threadIdx.x;
    int w = t >> 6, l = t & 63;
    int f0 = (l >> 4) * 32 + (l & 15) * 2;   // even feature; f1 = f0+1 (same head)
    int fp = f0 >> 1;
    int hd = l >> 4;                          // head index

    float2 bs2 = ((const float2*)bias)[fp];
    float2 gv = ((const float2*)gamma)[fp];
    float2 bev = ((const float2*)beta)[fp];

    int n0 = (blockIdx.x * 4 + w) * 4;
    int nend = n0 + 4; if (nend > NN) nend = NN;

    for (int i = n0; i < nend; ++i) {
        unsigned rp = *(const unsigned*)&resid[(size_t)i * rstride + f0];  // early issue
        int b0 = off[i], b1 = off[i + 1];

        float lA = 0.f, aA0 = 0.f, aA1 = 0.f;
        float lB = 0.f, aB0 = 0.f, aB1 = 0.f;
        int pos = b0;
        int sA = 0, sB = 0; float pA = 0.f, pB = 0.f;
        bool have = (pos + 2 <= b1);
        if (have) {
            sA = csr_se[pos].x; sB = csr_se[pos + 1].x;
            pA = pe[(size_t)pos * 4 + hd]; pB = pe[(size_t)(pos + 1) * 4 + hd];
        }
        while (have) {
            bool haven = (pos + 4 <= b1);
            int nsA = 0, nsB = 0; float npA = 0.f, npB = 0.f;
            if (haven) {
                nsA = csr_se[pos + 2].x; nsB = csr_se[pos + 3].x;
                npA = pe[(size_t)(pos + 2) * 4 + hd]; npB = pe[(size_t)(pos + 3) * 4 + hd];
            }
            unsigned xlA = *(const unsigned*)&C[(size_t)sA * STRIDE + f0];
            unsigned xlB = *(const unsigned*)&C[(size_t)sB * STRIDE + f0];
            lA += pA; lB += pB;
            aA0 = fmaf(pA, bflo(xlA), aA0);
            aA1 = fmaf(pA, bfhi(xlA), aA1);
            aB0 = fmaf(pB, bflo(xlB), aB0);
            aB1 = fmaf(pB, bfhi(xlB), aB1);
            pos += 2;
            sA = nsA; sB = nsB; pA = npA; pB = npB;
            have = haven;
        }
        if (pos < b1) {
            int s1 = csr_se[pos].x;
            float p1 = pe[(size_t)pos * 4 + hd];
            unsigned xlv = *(const unsigned*)&C[(size_t)s1 * STRIDE + f0];
            lA += p1;
            aA0 = fmaf(p1, bflo(xlv), aA0);
            aA1 = fmaf(p1, bfhi(xlv), aA1);
        }
        float l_run = lA + lB;
        float acc0 = aA0 + aB0, acc1 = aA1 + aB1;

        float inv = 1.f / (l_run + 1e-16f);
        float o0 = fmaf(acc0, inv, bs2.x);
        float o1 = fmaf(acc1, inv, bs2.y);
        o0 = o0 > 0.f ? o0 : (__expf(o0) - 1.f);            // ELU
        o1 = o1 > 0.f ? o1 : (__expf(o1) - 1.f);
        float v0 = o0 + bflo(rp), v1 = o1 + bfhi(rp);       // + residual
        // in-wave LayerNorm over 128 features (2 per lane)
        float s = v0 + v1;
#pragma unroll
        for (int o = 32; o > 0; o >>= 1) s += __shfl_xor(s, o, 64);
        float mean = s * (1.f / 128.f);
        float d0 = v0 - mean, d1 = v1 - mean;
        float q = fmaf(d0, d0, d1 * d1);
#pragma unroll
        for (int o = 32; o > 0; o >>= 1) q += __shfl_xor(q, o, 64);
        float rstd = rsqrtf(q * (1.f / 128.f) + 1e-5f);
        float r0 = fmaf(d0 * rstd, gv.x, bev.x);
        float r1 = fmaf(d1 * rstd, gv.y, bev.y);
        unsigned op = (unsigned)(unsigned short)f2bf(r0) |
                      (((unsigned)(unsigned short)f2bf(r1)) << 16);
        *(unsigned*)&outb[(size_t)i * 128 + f0] = op;
    }
}

extern "C" void kernel_launch(void* const* d_in, const int* in_sizes, int n_in,
                              void* d_out, int out_size, void* d_ws, size_t ws_size,
                              hipStream_t stream) {
    (void)in_sizes; (void)n_in; (void)out_size; (void)ws_size;
    const float* x     = (const float*)d_in[0];
    const float* ea    = (const float*)d_in[1];
    const float* Wl1   = (const float*)d_in[2];
    const float* bl1   = (const float*)d_in[3];
    const float* Wr1   = (const float*)d_in[4];
    const float* br1   = (const float*)d_in[5];
    const float* We1   = (const float*)d_in[6];
    const float* att1  = (const float*)d_in[7];
    const float* bias1 = (const float*)d_in[8];
    const float* Wl2   = (const float*)d_in[9];
    const float* bl2   = (const float*)d_in[10];
    const float* Wr2   = (const float*)d_in[11];
    const float* br2   = (const float*)d_in[12];
    const float* We2   = (const float*)d_in[13];
    const float* att2  = (const float*)d_in[14];
    const float* bias2 = (const float*)d_in[15];
    const float* Wres  = (const float*)d_in[16];
    const float* bres  = (const float*)d_in[17];
    const float* Wout  = (const float*)d_in[18];
    const float* bout  = (const float*)d_in[19];
    const float* g1    = (const float*)d_in[20];
    const float* bn1   = (const float*)d_in[21];
    const float* g2    = (const float*)d_in[22];
    const float* bn2   = (const float*)d_in[23];
    const float* go    = (const float*)d_in[24];
    const float* bo    = (const float*)d_in[25];
    const int*   ei    = (const int*)d_in[26];
    const int* srcv = ei;
    const int* dstv = ei + NE;
    float* outp = (float*)d_out;

    char* p = (char*)d_ws;
    auto carve = [&](size_t bytes) {
        char* r = p;
        p += (bytes + 255) & ~(size_t)255;
        return r;
    };
    short* xb    = (short*)carve((size_t)NN * KP1 * 2);
    short* Wt1   = (short*)carve((size_t)384 * KP1 * 2);
    short* Wt2   = (short*)carve((size_t)256 * 128 * 2);
    short* Wt3   = (short*)carve((size_t)128 * 128 * 2);
    short* WeT1  = (short*)carve((size_t)128 * 32 * 2);
    short* WeT2  = (short*)carve((size_t)128 * 32 * 2);
    short* attB1 = (short*)carve((size_t)16 * 128 * 2);
    short* attB2 = (short*)carve((size_t)16 * 128 * 2);
    float* bcat1 = (float*)carve(384 * 4);
    float* bcat2 = (float*)carve(256 * 4);
    short* C1    = (short*)carve((size_t)NN * 384 * 2);   // bf16 [xl|xr|res]
    short* h1b   = (short*)carve((size_t)NN * 128 * 2);
    short* h2b   = (short*)carve((size_t)NN * 128 * 2);
    int* off     = (int*)carve((size_t)(NN + 1) * 4);
    int* cur     = (int*)carve((size_t)NN * 4);
    int* bsum    = (int*)carve(256 * 4);
    int2* csr_se = (int2*)carve((size_t)NE * 8);          // {src, edge_id} per CSR position
    int* dstp    = (int*)carve((size_t)NE * 4);           // filled contiguously from off
    float* pe    = (float*)carve((size_t)NE * 4 * 4);     // 8 MB, exp(score) per edge x head

    short* C2 = C1;                                  // stride 256, reuse after layer 1

    const int NB = (NN + 255) / 256;                 // 196

    // ---- CSR build ----
    hipMemsetAsync(cur, 0, (size_t)NN * 4, stream);
    k_count<<<(NE + 255) / 256, 256, 0, stream>>>(dstv, cur);
    k_scan1<<<NB, 256, 0, stream>>>(cur, off, bsum);
    k_scan2<<<1, 256, 0, stream>>>(bsum, NB);
    k_scan3c<<<(NN + 256) / 256, 256, 0, stream>>>(off, bsum, cur);
    k_scatter<<<(NE + 255) / 256, 256, 0, stream>>>(srcv, dstv, cur, csr_se);
    k_fill_dst<<<NB, 256, 0, stream>>>(off, dstp);

    // ---- prep ----
    k_cvt_x<<<((size_t)NN * KP1 + 255) / 256, 256, 0, stream>>>(x, xb);
    int prep_total = 384 * KP1 + 256 * 128 + 128 * 128 + 384 + 256 + 2 * 128 * 32 + 2 * 16 * 128;
    k_prep_w<<<(prep_total + 255) / 256, 256, 0, stream>>>(Wl1, Wr1, Wres, Wl2, Wr2, Wout,
                                                           bl1, br1, bres, bl2, br2,
                                                           We1, We2, att1, att2,
                                                           Wt1, Wt2, Wt3, bcat1, bcat2,
                                                           WeT1, WeT2, attB1, attB2);

    int mb  = (NN + 127) / 128;                      // 391
    int ebk = (NE + 127) / 128;                      // 3907
    int gagg = (NN + 15) / 16;                       // 3125 blocks (4 waves x 4 nodes)

    // ---- layer 1 ----
    k_mfma_gemm<true><<<dim3(mb, 3), 256, 0, stream>>>(xb, Wt1, bcat1, nullptr, C1, NN, KP1, 384);
    k_edge_score<384><<<ebk, 512, 0, stream>>>(csr_se, dstp, ea, WeT1, attB1, C1, pe);
    k_fused_agg<384><<<gagg, 256, 0, stream>>>(off, csr_se, pe, C1,
                                               C1 + 256, 384, bias1, g1, bn1, h1b);
    // ---- layer 2 ----
    k_mfma_gemm<true><<<dim3(mb, 2), 256, 0, stream>>>(h1b, Wt2, bcat2, nullptr, C2, NN, 128, 256);
    k_edge_score<256><<<ebk, 512, 0, stream>>>(csr_se, dstp, ea, WeT2, attB2, C2, pe);
    k_fused_agg<256><<<gagg, 256, 0, stream>>>(off, csr_se, pe, C2,
                                               h1b, 128, bias2, g2, bn2, h2b);
    // ---- output: GEMM + fused LN ----
    k_gemm_ln<<<mb, 256, 0, stream>>>(h2b, Wt3, bout, go, bo, outp, NN);
}

// Round 11
// 481.554 us; speedup vs baseline: 1.0141x; 1.0141x over previous
//
#include <hip/hip_runtime.h>
#include <hip/hip_bf16.h>
#include <math.h>
#include <stdint.h>

#define NN 50000
#define NE 500000
#define DIN 264
#define KP1 288      // DIN padded to multiple of 32
#define HID 128
#define EDIM 16

typedef __attribute__((ext_vector_type(8))) short short8;
typedef __attribute__((ext_vector_type(4))) float f32x4;

__device__ __forceinline__ short f2bf(float v) {
    union { float f; unsigned u; } x; x.f = v;
    unsigned r = x.u + 0x7fff + ((x.u >> 16) & 1);
    return (short)(r >> 16);
}
__device__ __forceinline__ float bf2f(short v) {
    union { float f; unsigned u; } x;
    x.u = ((unsigned)(unsigned short)v) << 16;
    return x.f;
}
// unpack two bf16 packed in a dword
__device__ __forceinline__ float bflo(unsigned u) {
    union { float f; unsigned u; } x; x.u = u << 16; return x.f;
}
__device__ __forceinline__ float bfhi(unsigned u) {
    union { float f; unsigned u; } x; x.u = u & 0xffff0000u; return x.f;
}
__device__ __forceinline__ unsigned pk2bf(float a, float b) {
    return (unsigned)(unsigned short)f2bf(a) | ((unsigned)(unsigned short)f2bf(b) << 16);
}

__device__ __forceinline__ void gload_lds16(const void* g, void* l) {
    __builtin_amdgcn_global_load_lds(
        (const __attribute__((address_space(1))) unsigned int*)g,
        (__attribute__((address_space(3))) unsigned int*)l, 16, 0, 0);
}

// ---------------- CSR build (dst -> in-edges) ----------------
__global__ void k_count(const int* __restrict__ dst, int* __restrict__ cnt) {
    int e = blockIdx.x * blockDim.x + threadIdx.x;
    if (e < NE) atomicAdd(&cnt[dst[e]], 1);
}

__global__ __launch_bounds__(256) void k_scan1(const int* __restrict__ cnt,
                                               int* __restrict__ off, int* __restrict__ bsum) {
    __shared__ int buf[256];
    int b = blockIdx.x, t = threadIdx.x;
    int i = b * 256 + t;
    int v = (i < NN) ? cnt[i] : 0;
    buf[t] = v; __syncthreads();
    for (int s = 1; s < 256; s <<= 1) {
        int u = (t >= s) ? buf[t - s] : 0; __syncthreads();
        buf[t] += u; __syncthreads();
    }
    if (i < NN) off[i + 1] = buf[t];
    if (t == 255) bsum[b] = buf[255];
}

__global__ void k_scan2(int* __restrict__ bsum, int nb) {
    __shared__ int buf[256];
    int t = threadIdx.x;
    int o = (t < nb) ? bsum[t] : 0;
    buf[t] = o; __syncthreads();
    for (int s = 1; s < 256; s <<= 1) {
        int u = (t >= s) ? buf[t - s] : 0; __syncthreads();
        buf[t] += u; __syncthreads();
    }
    if (t < nb) bsum[t] = buf[t] - o;   // exclusive
}

// finalize offsets AND copy to cur in one pass
__global__ void k_scan3c(int* __restrict__ off, const int* __restrict__ bsum,
                         int* __restrict__ cur) {
    int j = blockIdx.x * 256 + threadIdx.x;   // 0..NN
    if (j > NN) return;
    int v = (j == 0) ? 0 : off[j] + bsum[(j - 1) >> 8];
    off[j] = v;
    if (j < NN) cur[j] = v;
}

// ONE 8B scattered write per edge (1 dirty line, vs 3 for split arrays)
__global__ void k_scatter(const int* __restrict__ src, const int* __restrict__ dst,
                          int* __restrict__ cur, int2* __restrict__ csr_se) {
    int e = blockIdx.x * blockDim.x + threadIdx.x;
    if (e < NE) {
        int d = dst[e];
        int p = atomicAdd(&cur[d], 1);
        csr_se[p] = make_int2(src[e], e);
    }
}

// dstp is constant per CSR segment -> fill CONTIGUOUSLY from off (no scatter)
__global__ void k_fill_dst(const int* __restrict__ off, int* __restrict__ dstp) {
    int i = blockIdx.x * 256 + threadIdx.x;
    if (i < NN) {
        int b0 = off[i], b1 = off[i + 1];
        for (int p = b0; p < b1; ++p) dstp[p] = i;
    }
}

// ---------------- weight/bias/input prep ----------------
__global__ void k_cvt_x(const float* __restrict__ x, short* __restrict__ xb) {
    int idx = blockIdx.x * 256 + threadIdx.x;
    if (idx >= NN * KP1) return;
    int i = idx / KP1, k = idx - i * KP1;
    xb[idx] = (k < DIN) ? f2bf(x[(size_t)i * DIN + k]) : (short)0;
}

// all weight transposes + bias concats + att block-diag expansion in ONE dispatch
__global__ void k_prep_w(const float* __restrict__ Wl1, const float* __restrict__ Wr1,
                         const float* __restrict__ Wres, const float* __restrict__ Wl2,
                         const float* __restrict__ Wr2, const float* __restrict__ Wout,
                         const float* __restrict__ bl1, const float* __restrict__ br1,
                         const float* __restrict__ bres, const float* __restrict__ bl2,
                         const float* __restrict__ br2,
                         const float* __restrict__ We1, const float* __restrict__ We2,
                         const float* __restrict__ att1, const float* __restrict__ att2,
                         short* __restrict__ Wt1, short* __restrict__ Wt2,
                         short* __restrict__ Wt3, float* __restrict__ bcat1,
                         float* __restrict__ bcat2,
                         short* __restrict__ WeT1, short* __restrict__ WeT2,
                         short* __restrict__ attB1, short* __restrict__ attB2) {
    int idx = blockIdx.x * 256 + threadIdx.x;
    if (idx < 384 * KP1) {
        int n = idx / KP1, k = idx - n * KP1;
        float v = 0.f;
        if (k < DIN) {
            const float* W = (n < 128) ? Wl1 : ((n < 256) ? Wr1 : Wres);
            v = W[(size_t)k * 128 + (n & 127)];
        }
        Wt1[idx] = f2bf(v);
        return;
    }
    idx -= 384 * KP1;
    if (idx < 256 * 128) {
        int n = idx >> 7, k = idx & 127;
        const float* W = (n < 128) ? Wl2 : Wr2;
        Wt2[idx] = f2bf(W[(size_t)k * 128 + (n & 127)]);
        return;
    }
    idx -= 256 * 128;
    if (idx < 128 * 128) {
        int n = idx >> 7, k = idx & 127;
        Wt3[idx] = f2bf(Wout[(size_t)k * 128 + n]);
        return;
    }
    idx -= 128 * 128;
    if (idx < 384) {
        bcat1[idx] = (idx < 128) ? bl1[idx] : ((idx < 256) ? br1[idx - 128] : bres[idx - 256]);
        return;
    }
    idx -= 384;
    if (idx < 256) {
        bcat2[idx] = (idx < 128) ? bl2[idx] : br2[idx - 128];
        return;
    }
    idx -= 256;
    if (idx < 128 * 32) {
        int n = idx >> 5, k = idx & 31;
        WeT1[idx] = (k < EDIM) ? f2bf(We1[(size_t)k * 128 + n]) : (short)0;
        return;
    }
    idx -= 128 * 32;
    if (idx < 128 * 32) {
        int n = idx >> 5, k = idx & 31;
        WeT2[idx] = (k < EDIM) ? f2bf(We2[(size_t)k * 128 + n]) : (short)0;
        return;
    }
    idx -= 128 * 32;
    if (idx < 16 * 128) {
        int n = idx >> 7, k = idx & 127;
        attB1[idx] = (n == (k >> 5)) ? f2bf(att1[k]) : (short)0;
        return;
    }
    idx -= 16 * 128;
    if (idx < 16 * 128) {
        int n = idx >> 7, k = idx & 127;
        attB2[idx] = (n == (k >> 5)) ? f2bf(att2[k]) : (short)0;
    }
}

// gather edge_attr rows into CSR order, f32 -> bf16, K padded 16->32 with zeros
__global__ __launch_bounds__(256) void k_gather_ea(const int2* __restrict__ csr_se,
                                                   const float* __restrict__ ea,
                                                   short* __restrict__ eaperm) {
    int pos = blockIdx.x * 256 + threadIdx.x;
    if (pos >= NE) return;
    int e = csr_se[pos].y;
    const float4* r = (const float4*)(ea + (size_t)e * EDIM);
    float4 v0 = r[0], v1 = r[1], v2 = r[2], v3 = r[3];
    uint4 w0 = make_uint4(pk2bf(v0.x, v0.y), pk2bf(v0.z, v0.w),
                          pk2bf(v1.x, v1.y), pk2bf(v1.z, v1.w));
    uint4 w1 = make_uint4(pk2bf(v2.x, v2.y), pk2bf(v2.z, v2.w),
                          pk2bf(v3.x, v3.y), pk2bf(v3.z, v3.w));
    uint4* o = (uint4*)(eaperm + (size_t)pos * 32);
    o[0] = w0; o[1] = w1;
    o[2] = make_uint4(0, 0, 0, 0);
    o[3] = make_uint4(0, 0, 0, 0);
}

// ---------------- bf16 MFMA GEMM: C[M x NS] = A[M x Kpad] @ Bt[NS x Kpad]^T + bias ----------------
template <bool BF16OUT>
__global__ __launch_bounds__(256) void k_mfma_gemm(const short* __restrict__ A,
                                                   const short* __restrict__ Bt,
                                                   const float* __restrict__ bias,
                                                   float* __restrict__ Cf,
                                                   short* __restrict__ Cb,
                                                   int M, int Kpad, int NS) {
    __shared__ short As[128 * 32];
    __shared__ short Bs[128 * 32];
    int t = threadIdx.x;
    int lane = t & 63, wid = t >> 6;
    int wm = (wid & 1) * 64, wn = (wid >> 1) * 64;
    int cl = lane & 15, quad = lane >> 4;
    int row0 = blockIdx.x * 128;
    int col0 = blockIdx.y * 128;

    f32x4 acc[4][4];
#pragma unroll
    for (int i = 0; i < 4; ++i)
#pragma unroll
        for (int j = 0; j < 4; ++j) acc[i][j] = (f32x4)0.f;

    for (int k0 = 0; k0 < Kpad; k0 += 32) {
#pragma unroll
        for (int r = 0; r < 2; ++r) {
            int c = t + r * 256;                     // chunk 0..511
            int m = c >> 2;
            int row = row0 + m; if (row >= M) row = M - 1;
            const char* ga = (const char*)A + ((size_t)row * Kpad + k0) * 2 + (c & 3) * 16;
            gload_lds16(ga, (char*)As + c * 16);
            int n = col0 + m;
            const char* gb = (const char*)Bt + ((size_t)n * Kpad + k0) * 2 + (c & 3) * 16;
            gload_lds16(gb, (char*)Bs + c * 16);
        }
        __syncthreads();

        short8 a[4], b[4];
#pragma unroll
        for (int mi = 0; mi < 4; ++mi)
            a[mi] = *(const short8*)&As[(wm + mi * 16 + cl) * 32 + quad * 8];
#pragma unroll
        for (int ni = 0; ni < 4; ++ni)
            b[ni] = *(const short8*)&Bs[(wn + ni * 16 + cl) * 32 + quad * 8];
#pragma unroll
        for (int mi = 0; mi < 4; ++mi)
#pragma unroll
            for (int ni = 0; ni < 4; ++ni)
                acc[mi][ni] = __builtin_amdgcn_mfma_f32_16x16x32_bf16(a[mi], b[ni], acc[mi][ni], 0, 0, 0);
        __syncthreads();
    }

#pragma unroll
    for (int mi = 0; mi < 4; ++mi)
#pragma unroll
        for (int ni = 0; ni < 4; ++ni) {
            int col = col0 + wn + ni * 16 + cl;
            float bv = bias[col];
#pragma unroll
            for (int r = 0; r < 4; ++r) {
                int row = row0 + wm + mi * 16 + quad * 4 + r;
                if (row < M) {
                    float v = acc[mi][ni][r] + bv;
                    if (BF16OUT) Cb[(size_t)row * NS + col] = f2bf(v);
                    else         Cf[(size_t)row * NS + col] = v;
                }
            }
        }
}

// ---------------- GEMM (M x 128 @ 128x128) with fused LayerNorm epilogue ----------------
__global__ __launch_bounds__(256) void k_gemm_ln(const short* __restrict__ A,
                                                 const short* __restrict__ Bt,
                                                 const float* __restrict__ bias,
                                                 const float* __restrict__ gamma,
                                                 const float* __restrict__ beta,
                                                 float* __restrict__ out, int M) {
    __shared__ short As[128 * 32];
    __shared__ short Bs[128 * 32];
    __shared__ float redS[128][2];
    int t = threadIdx.x;
    int lane = t & 63, wid = t >> 6;
    int wm = (wid & 1) * 64, wn = (wid >> 1) * 64;
    int cl = lane & 15, quad = lane >> 4;
    int row0 = blockIdx.x * 128;
    int wh = wid >> 1;                 // which 64-col half this wave owns

    f32x4 acc[4][4];
#pragma unroll
    for (int i = 0; i < 4; ++i)
#pragma unroll
        for (int j = 0; j < 4; ++j) acc[i][j] = (f32x4)0.f;

    for (int k0 = 0; k0 < 128; k0 += 32) {
#pragma unroll
        for (int r = 0; r < 2; ++r) {
            int c = t + r * 256;
            int m = c >> 2;
            int row = row0 + m; if (row >= M) row = M - 1;
            const char* ga = (const char*)A + ((size_t)row * 128 + k0) * 2 + (c & 3) * 16;
            gload_lds16(ga, (char*)As + c * 16);
            const char* gb = (const char*)Bt + ((size_t)m * 128 + k0) * 2 + (c & 3) * 16;
            gload_lds16(gb, (char*)Bs + c * 16);
        }
        __syncthreads();

        short8 a[4], b[4];
#pragma unroll
        for (int mi = 0; mi < 4; ++mi)
            a[mi] = *(const short8*)&As[(wm + mi * 16 + cl) * 32 + quad * 8];
#pragma unroll
        for (int ni = 0; ni < 4; ++ni)
            b[ni] = *(const short8*)&Bs[(wn + ni * 16 + cl) * 32 + quad * 8];
#pragma unroll
        for (int mi = 0; mi < 4; ++mi)
#pragma unroll
            for (int ni = 0; ni < 4; ++ni)
                acc[mi][ni] = __builtin_amdgcn_mfma_f32_16x16x32_bf16(a[mi], b[ni], acc[mi][ni], 0, 0, 0);
        __syncthreads();
    }

    // per-column params for this thread's 4 column slots
    float bv[4], gv[4], bev[4];
#pragma unroll
    for (int ni = 0; ni < 4; ++ni) {
        int col = wn + ni * 16 + cl;
        bv[ni] = bias[col]; gv[ni] = gamma[col]; bev[ni] = beta[col];
    }

    // ---- row sums (over this wave's 64 cols) ----
    float s[4][4];
#pragma unroll
    for (int mi = 0; mi < 4; ++mi)
#pragma unroll
        for (int r = 0; r < 4; ++r) {
            float v = (acc[mi][0][r] + bv[0]) + (acc[mi][1][r] + bv[1]) +
                      (acc[mi][2][r] + bv[2]) + (acc[mi][3][r] + bv[3]);
            v += __shfl_xor(v, 1, 64);
            v += __shfl_xor(v, 2, 64);
            v += __shfl_xor(v, 4, 64);
            v += __shfl_xor(v, 8, 64);
            s[mi][r] = v;
        }
    if (cl == 0) {
#pragma unroll
        for (int mi = 0; mi < 4; ++mi)
#pragma unroll
            for (int r = 0; r < 4; ++r)
                redS[wm + mi * 16 + quad * 4 + r][wh] = s[mi][r];
    }
    __syncthreads();
    float mean[4][4];
#pragma unroll
    for (int mi = 0; mi < 4; ++mi)
#pragma unroll
        for (int r = 0; r < 4; ++r) {
            int rl = wm + mi * 16 + quad * 4 + r;
            mean[mi][r] = (redS[rl][0] + redS[rl][1]) * (1.f / 128.f);
        }
    __syncthreads();

    // ---- row variances ----
#pragma unroll
    for (int mi = 0; mi < 4; ++mi)
#pragma unroll
        for (int r = 0; r < 4; ++r) {
            float q = 0.f;
#pragma unroll
            for (int ni = 0; ni < 4; ++ni) {
                float d = acc[mi][ni][r] + bv[ni] - mean[mi][r];
                q = fmaf(d, d, q);
            }
            q += __shfl_xor(q, 1, 64);
            q += __shfl_xor(q, 2, 64);
            q += __shfl_xor(q, 4, 64);
            q += __shfl_xor(q, 8, 64);
            s[mi][r] = q;
        }
    if (cl == 0) {
#pragma unroll
        for (int mi = 0; mi < 4; ++mi)
#pragma unroll
            for (int r = 0; r < 4; ++r)
                redS[wm + mi * 16 + quad * 4 + r][wh] = s[mi][r];
    }
    __syncthreads();

#pragma unroll
    for (int mi = 0; mi < 4; ++mi)
#pragma unroll
        for (int r = 0; r < 4; ++r) {
            int rl = wm + mi * 16 + quad * 4 + r;
            int row = row0 + rl;
            if (row < M) {
                float rstd = rsqrtf((redS[rl][0] + redS[rl][1]) * (1.f / 128.f) + 1e-5f);
#pragma unroll
                for (int ni = 0; ni < 4; ++ni) {
                    int col = wn + ni * 16 + cl;
                    float d = acc[mi][ni][r] + bv[ni] - mean[mi][r];
                    out[(size_t)row * 128 + col] = fmaf(d * rstd, gv[ni], bev[ni]);
                }
            }
        }
}

// ---------------- edge score kernel (round-7 variant: eaperm staging, 512 thr) ----------------
// Per block: 128 CSR-ordered edges, 8 waves.
// Phase 1: ee[128x128] = eaperm_tile @ WeT^T via MFMA, fragments DIRECT from
//          global (eaperm rows coalesced 1KB/wave; WeT 8KB L1-resident).
//          Each wave owns a 64-edge x 32-f quadrant (acc[4][2]).
// Phase 2: g = leaky(ee + xl[src] + xr[dst]) -> Gs (lane=f: coalesced row reads).
// Phase 3: S[128x16] = g @ attB^T (attB block-diag; Ab/Gs stride 136).
// Phase 4: pe[e,h] = exp(S).
template <int STRIDE>
__global__ __launch_bounds__(512) void k_edge_score(const short* __restrict__ eaperm,
                                                    const short* __restrict__ WeT,
                                                    const short* __restrict__ attB,
                                                    const int2* __restrict__ csr_se,
                                                    const int* __restrict__ dstp,
                                                    const short* __restrict__ C,
                                                    float* __restrict__ pe) {
    __shared__ short Gs[128 * 136];
    __shared__ short Ab[16 * 136];
    __shared__ int sS[128], sD[128];
    int t = threadIdx.x;
    int lane = t & 63, wid = t >> 6;          // 8 waves
    int wm2 = (wid & 1) * 64;                 // edge half
    int wn2 = (wid >> 1) * 32;                // f quarter
    int cl = lane & 15, quad = lane >> 4;
    long e0 = (long)blockIdx.x * 128;

    if (t < 128) {
        long ep = e0 + t; if (ep >= NE) ep = NE - 1;
        sS[t] = csr_se[ep].x;
        sD[t] = dstp[ep];
    } else if (t < 384) {
        int u = t - 128;                      // 0..255 -> 16 rows x 16 chunks of 8 shorts
        int rr = u >> 4, cc = (u & 15) * 8;
        *(short8*)&Ab[rr * 136 + cc] = *(const short8*)&attB[rr * 128 + cc];
    }

    // ---- phase 1: fragments direct from global, 8 MFMAs ----
    short8 a[4], b[2];
#pragma unroll
    for (int mi = 0; mi < 4; ++mi) {
        long e = e0 + wm2 + mi * 16 + cl; if (e >= NE) e = NE - 1;
        a[mi] = *(const short8*)&eaperm[e * 32 + quad * 8];
    }
#pragma unroll
    for (int ni = 0; ni < 2; ++ni)
        b[ni] = *(const short8*)&WeT[(size_t)(wn2 + ni * 16 + cl) * 32 + quad * 8];

    f32x4 acc[4][2];
#pragma unroll
    for (int i = 0; i < 4; ++i) { acc[i][0] = (f32x4)0.f; acc[i][1] = (f32x4)0.f; }
#pragma unroll
    for (int mi = 0; mi < 4; ++mi)
#pragma unroll
        for (int ni = 0; ni < 2; ++ni)
            acc[mi][ni] = __builtin_amdgcn_mfma_f32_16x16x32_bf16(a[mi], b[ni], acc[mi][ni], 0, 0, 0);
    __syncthreads();   // sS/sD/Ab ready

    // ---- phase 2: g = leaky(ee + xl + xr) -> Gs (coalesced: lanes = consecutive f) ----
#pragma unroll
    for (int mi = 0; mi < 4; ++mi) {
#pragma unroll
        for (int r = 0; r < 4; ++r) {
            int eloc = wm2 + mi * 16 + quad * 4 + r;
            const short* xlr = C + (size_t)sS[eloc] * STRIDE;
            const short* xrr = C + (size_t)sD[eloc] * STRIDE + 128;
            int f0 = wn2 + cl, f1 = wn2 + 16 + cl;
            float xl0 = bf2f(xlr[f0]), xr0 = bf2f(xrr[f0]);
            float xl1 = bf2f(xlr[f1]), xr1 = bf2f(xrr[f1]);
            float g0 = acc[mi][0][r] + xl0 + xr0;
            float g1 = acc[mi][1][r] + xl1 + xr1;
            g0 = fmaxf(g0, 0.2f * g0);
            g1 = fmaxf(g1, 0.2f * g1);
            Gs[eloc * 136 + f0] = f2bf(g0);
            Gs[eloc * 136 + f1] = f2bf(g1);
        }
    }
    __syncthreads();

    // ---- phase 3: scores = g @ attB^T (16 edges per wave, 4 MFMAs) ----
    f32x4 sacc = (f32x4)0.f;
    int em0 = wid * 16;
#pragma unroll
    for (int ks = 0; ks < 4; ++ks) {
        short8 ag = *(const short8*)&Gs[(em0 + cl) * 136 + ks * 32 + quad * 8];
        short8 bg = *(const short8*)&Ab[cl * 136 + ks * 32 + quad * 8];
        sacc = __builtin_amdgcn_mfma_f32_16x16x32_bf16(ag, bg, sacc, 0, 0, 0);
    }

    // ---- phase 4: exp + store (D layout: col=cl (head), row=quad*4+r (edge)) ----
    if (cl < 4) {
#pragma unroll
        for (int r = 0; r < 4; ++r) {
            long epos = e0 + em0 + quad * 4 + r;
            if (epos < NE) pe[epos * 4 + cl] = __expf(sacc[r]);
        }
    }
}

// ---------------- slim softmax-aggregate + epilogue ----------------
// ONE WAVE PER 4-NODE CHUNK. Per edge: csr_se + pe (per-head broadcast) + xl dword
// + 3 FMAs. No shfl, no exp (scores precomputed by k_edge_score). l_run needs no
// reduce: pe is uniform across each 16-lane head group. Two accumulator sets
// break the serial FMA chain; next-pair prefetch hides gather latency.
template <int STRIDE>
__global__ __launch_bounds__(256) void k_fused_agg(const int* __restrict__ off,
                                                   const int2* __restrict__ csr_se,
                                                   const float* __restrict__ pe,
                                                   const short* __restrict__ C,
                                                   const short* __restrict__ resid, int rstride,
                                                   const float* __restrict__ bias,
                                                   const float* __restrict__ gamma,
                                                   const float* __restrict__ beta,
                                                   short* __restrict__ outb) {
    int t = threadIdx.x;
    int w = t >> 6, l = t & 63;
    int f0 = (l >> 4) * 32 + (l & 15) * 2;   // even feature; f1 = f0+1 (same head)
    int fp = f0 >> 1;
    int hd = l >> 4;                          // head index

    float2 bs2 = ((const float2*)bias)[fp];
    float2 gv = ((const float2*)gamma)[fp];
    float2 bev = ((const float2*)beta)[fp];

    int n0 = (blockIdx.x * 4 + w) * 4;
    int nend = n0 + 4; if (nend > NN) nend = NN;

    for (int i = n0; i < nend; ++i) {
        unsigned rp = *(const unsigned*)&resid[(size_t)i * rstride + f0];  // early issue
        int b0 = off[i], b1 = off[i + 1];

        float lA = 0.f, aA0 = 0.f, aA1 = 0.f;
        float lB = 0.f, aB0 = 0.f, aB1 = 0.f;
        int pos = b0;
        int sA = 0, sB = 0; float pA = 0.f, pB = 0.f;
        bool have = (pos + 2 <= b1);
        if (have) {
            sA = csr_se[pos].x; sB = csr_se[pos + 1].x;
            pA = pe[(size_t)pos * 4 + hd]; pB = pe[(size_t)(pos + 1) * 4 + hd];
        }
        while (have) {
            bool haven = (pos + 4 <= b1);
            int nsA = 0, nsB = 0; float npA = 0.f, npB = 0.f;
            if (haven) {
                nsA = csr_se[pos + 2].x; nsB = csr_se[pos + 3].x;
                npA = pe[(size_t)(pos + 2) * 4 + hd]; npB = pe[(size_t)(pos + 3) * 4 + hd];
            }
            unsigned xlA = *(const unsigned*)&C[(size_t)sA * STRIDE + f0];
            unsigned xlB = *(const unsigned*)&C[(size_t)sB * STRIDE + f0];
            lA += pA; lB += pB;
            aA0 = fmaf(pA, bflo(xlA), aA0);
            aA1 = fmaf(pA, bfhi(xlA), aA1);
            aB0 = fmaf(pB, bflo(xlB), aB0);
            aB1 = fmaf(pB, bfhi(xlB), aB1);
            pos += 2;
            sA = nsA; sB = nsB; pA = npA; pB = npB;
            have = haven;
        }
        if (pos < b1) {
            int s1 = csr_se[pos].x;
            float p1 = pe[(size_t)pos * 4 + hd];
            unsigned xlv = *(const unsigned*)&C[(size_t)s1 * STRIDE + f0];
            lA += p1;
            aA0 = fmaf(p1, bflo(xlv), aA0);
            aA1 = fmaf(p1, bfhi(xlv), aA1);
        }
        float l_run = lA + lB;
        float acc0 = aA0 + aB0, acc1 = aA1 + aB1;

        float inv = 1.f / (l_run + 1e-16f);
        float o0 = fmaf(acc0, inv, bs2.x);
        float o1 = fmaf(acc1, inv, bs2.y);
        o0 = o0 > 0.f ? o0 : (__expf(o0) - 1.f);            // ELU
        o1 = o1 > 0.f ? o1 : (__expf(o1) - 1.f);
        float v0 = o0 + bflo(rp), v1 = o1 + bfhi(rp);       // + residual
        // in-wave LayerNorm over 128 features (2 per lane)
        float s = v0 + v1;
#pragma unroll
        for (int o = 32; o > 0; o >>= 1) s += __shfl_xor(s, o, 64);
        float mean = s * (1.f / 128.f);
        float d0 = v0 - mean, d1 = v1 - mean;
        float q = fmaf(d0, d0, d1 * d1);
#pragma unroll
        for (int o = 32; o > 0; o >>= 1) q += __shfl_xor(q, o, 64);
        float rstd = rsqrtf(q * (1.f / 128.f) + 1e-5f);
        float r0 = fmaf(d0 * rstd, gv.x, bev.x);
        float r1 = fmaf(d1 * rstd, gv.y, bev.y);
        unsigned op = (unsigned)(unsigned short)f2bf(r0) |
                      (((unsigned)(unsigned short)f2bf(r1)) << 16);
        *(unsigned*)&outb[(size_t)i * 128 + f0] = op;
    }
}

extern "C" void kernel_launch(void* const* d_in, const int* in_sizes, int n_in,
                              void* d_out, int out_size, void* d_ws, size_t ws_size,
                              hipStream_t stream) {
    (void)in_sizes; (void)n_in; (void)out_size; (void)ws_size;
    const float* x     = (const float*)d_in[0];
    const float* ea    = (const float*)d_in[1];
    const float* Wl1   = (const float*)d_in[2];
    const float* bl1   = (const float*)d_in[3];
    const float* Wr1   = (const float*)d_in[4];
    const float* br1   = (const float*)d_in[5];
    const float* We1   = (const float*)d_in[6];
    const float* att1  = (const float*)d_in[7];
    const float* bias1 = (const float*)d_in[8];
    const float* Wl2   = (const float*)d_in[9];
    const float* bl2   = (const float*)d_in[10];
    const float* Wr2   = (const float*)d_in[11];
    const float* br2   = (const float*)d_in[12];
    const float* We2   = (const float*)d_in[13];
    const float* att2  = (const float*)d_in[14];
    const float* bias2 = (const float*)d_in[15];
    const float* Wres  = (const float*)d_in[16];
    const float* bres  = (const float*)d_in[17];
    const float* Wout  = (const float*)d_in[18];
    const float* bout  = (const float*)d_in[19];
    const float* g1    = (const float*)d_in[20];
    const float* bn1   = (const float*)d_in[21];
    const float* g2    = (const float*)d_in[22];
    const float* bn2   = (const float*)d_in[23];
    const float* go    = (const float*)d_in[24];
    const float* bo    = (const float*)d_in[25];
    const int*   ei    = (const int*)d_in[26];
    const int* srcv = ei;
    const int* dstv = ei + NE;
    float* outp = (float*)d_out;

    char* p = (char*)d_ws;
    auto carve = [&](size_t bytes) {
        char* r = p;
        p += (bytes + 255) & ~(size_t)255;
        return r;
    };
    short* xb    = (short*)carve((size_t)NN * KP1 * 2);
    short* Wt1   = (short*)carve((size_t)384 * KP1 * 2);
    short* Wt2   = (short*)carve((size_t)256 * 128 * 2);
    short* Wt3   = (short*)carve((size_t)128 * 128 * 2);
    short* WeT1  = (short*)carve((size_t)128 * 32 * 2);
    short* WeT2  = (short*)carve((size_t)128 * 32 * 2);
    short* attB1 = (short*)carve((size_t)16 * 128 * 2);
    short* attB2 = (short*)carve((size_t)16 * 128 * 2);
    float* bcat1 = (float*)carve(384 * 4);
    float* bcat2 = (float*)carve(256 * 4);
    short* C1    = (short*)carve((size_t)NN * 384 * 2);   // bf16 [xl|xr|res]
    short* h1b   = (short*)carve((size_t)NN * 128 * 2);
    short* h2b   = (short*)carve((size_t)NN * 128 * 2);
    int* off     = (int*)carve((size_t)(NN + 1) * 4);
    int* cur     = (int*)carve((size_t)NN * 4);
    int* bsum    = (int*)carve(256 * 4);
    int2* csr_se = (int2*)carve((size_t)NE * 8);          // {src, edge_id} per CSR position
    int* dstp    = (int*)carve((size_t)NE * 4);           // filled contiguously from off
    short* eaperm = (short*)carve((size_t)NE * 32 * 2);   // 32 MB, CSR-ordered bf16 ea (K pad 32)
    float* pe    = (float*)carve((size_t)NE * 4 * 4);     // 8 MB, exp(score) per edge x head

    short* C2 = C1;                                  // stride 256, reuse after layer 1

    const int NB = (NN + 255) / 256;                 // 196

    // ---- CSR build ----
    hipMemsetAsync(cur, 0, (size_t)NN * 4, stream);
    k_count<<<(NE + 255) / 256, 256, 0, stream>>>(dstv, cur);
    k_scan1<<<NB, 256, 0, stream>>>(cur, off, bsum);
    k_scan2<<<1, 256, 0, stream>>>(bsum, NB);
    k_scan3c<<<(NN + 256) / 256, 256, 0, stream>>>(off, bsum, cur);
    k_scatter<<<(NE + 255) / 256, 256, 0, stream>>>(srcv, dstv, cur, csr_se);
    k_fill_dst<<<NB, 256, 0, stream>>>(off, dstp);

    // ---- prep ----
    k_cvt_x<<<((size_t)NN * KP1 + 255) / 256, 256, 0, stream>>>(x, xb);
    int prep_total = 384 * KP1 + 256 * 128 + 128 * 128 + 384 + 256 + 2 * 128 * 32 + 2 * 16 * 128;
    k_prep_w<<<(prep_total + 255) / 256, 256, 0, stream>>>(Wl1, Wr1, Wres, Wl2, Wr2, Wout,
                                                           bl1, br1, bres, bl2, br2,
                                                           We1, We2, att1, att2,
                                                           Wt1, Wt2, Wt3, bcat1, bcat2,
                                                           WeT1, WeT2, attB1, attB2);
    k_gather_ea<<<(NE + 255) / 256, 256, 0, stream>>>(csr_se, ea, eaperm);

    int mb  = (NN + 127) / 128;                      // 391
    int ebk = (NE + 127) / 128;                      // 3907
    int gagg = (NN + 15) / 16;                       // 3125 blocks (4 waves x 4 nodes)

    // ---- layer 1 ----
    k_mfma_gemm<true><<<dim3(mb, 3), 256, 0, stream>>>(xb, Wt1, bcat1, nullptr, C1, NN, KP1, 384);
    k_edge_score<384><<<ebk, 512, 0, stream>>>(eaperm, WeT1, attB1, csr_se, dstp, C1, pe);
    k_fused_agg<384><<<gagg, 256, 0, stream>>>(off, csr_se, pe, C1,
                                               C1 + 256, 384, bias1, g1, bn1, h1b);
    // ---- layer 2 ----
    k_mfma_gemm<true><<<dim3(mb, 2), 256, 0, stream>>>(h1b, Wt2, bcat2, nullptr, C2, NN, 128, 256);
    k_edge_score<256><<<ebk, 512, 0, stream>>>(eaperm, WeT2, attB2, csr_se, dstp, C2, pe);
    k_fused_agg<256><<<gagg, 256, 0, stream>>>(off, csr_se, pe, C2,
                                               h1b, 128, bias2, g2, bn2, h2b);
    // ---- output: GEMM + fused LN ----
    k_gemm_ln<<<mb, 256, 0, stream>>>(h2b, Wt3, bout, go, bo, outp, NN);
}

// Round 12
// 460.381 us; speedup vs baseline: 1.0607x; 1.0460x over previous
//
#include <hip/hip_runtime.h>
#include <hip/hip_bf16.h>
#include <math.h>
#include <stdint.h>

#define NN 50000
#define NE 500000
#define DIN 264
#define KP1 288      // DIN padded to multiple of 32
#define HID 128
#define EDIM 16

typedef __attribute__((ext_vector_type(8))) short short8;
typedef __attribute__((ext_vector_type(4))) float f32x4;

__device__ __forceinline__ short f2bf(float v) {
    union { float f; unsigned u; } x; x.f = v;
    unsigned r = x.u + 0x7fff + ((x.u >> 16) & 1);
    return (short)(r >> 16);
}
__device__ __forceinline__ float bf2f(short v) {
    union { float f; unsigned u; } x;
    x.u = ((unsigned)(unsigned short)v) << 16;
    return x.f;
}
// unpack two bf16 packed in a dword
__device__ __forceinline__ float bflo(unsigned u) {
    union { float f; unsigned u; } x; x.u = u << 16; return x.f;
}
__device__ __forceinline__ float bfhi(unsigned u) {
    union { float f; unsigned u; } x; x.u = u & 0xffff0000u; return x.f;
}
__device__ __forceinline__ unsigned pk2bf(float a, float b) {
    return (unsigned)(unsigned short)f2bf(a) | ((unsigned)(unsigned short)f2bf(b) << 16);
}

__device__ __forceinline__ void gload_lds16(const void* g, void* l) {
    __builtin_amdgcn_global_load_lds(
        (const __attribute__((address_space(1))) unsigned int*)g,
        (__attribute__((address_space(3))) unsigned int*)l, 16, 0, 0);
}

// ---------------- CSR build (dst -> in-edges) ----------------
__global__ __launch_bounds__(256) void k_scan1(const int* __restrict__ cnt,
                                               int* __restrict__ off, int* __restrict__ bsum) {
    __shared__ int buf[256];
    int b = blockIdx.x, t = threadIdx.x;
    int i = b * 256 + t;
    int v = (i < NN) ? cnt[i] : 0;
    buf[t] = v; __syncthreads();
    for (int s = 1; s < 256; s <<= 1) {
        int u = (t >= s) ? buf[t - s] : 0; __syncthreads();
        buf[t] += u; __syncthreads();
    }
    if (i < NN) off[i + 1] = buf[t];
    if (t == 255) bsum[b] = buf[255];
}

__global__ void k_scan2(int* __restrict__ bsum, int nb) {
    __shared__ int buf[256];
    int t = threadIdx.x;
    int o = (t < nb) ? bsum[t] : 0;
    buf[t] = o; __syncthreads();
    for (int s = 1; s < 256; s <<= 1) {
        int u = (t >= s) ? buf[t - s] : 0; __syncthreads();
        buf[t] += u; __syncthreads();
    }
    if (t < nb) bsum[t] = buf[t] - o;   // exclusive
}

// finalize offsets AND copy to cur in one pass
__global__ void k_scan3c(int* __restrict__ off, const int* __restrict__ bsum,
                         int* __restrict__ cur) {
    int j = blockIdx.x * 256 + threadIdx.x;   // 0..NN
    if (j > NN) return;
    int v = (j == 0) ? 0 : off[j] + bsum[(j - 1) >> 8];
    off[j] = v;
    if (j < NN) cur[j] = v;
}

// ONE 8B scattered write per edge (1 dirty line, vs 3 for split arrays)
__global__ void k_scatter(const int* __restrict__ src, const int* __restrict__ dst,
                          int* __restrict__ cur, int2* __restrict__ csr_se) {
    int e = blockIdx.x * blockDim.x + threadIdx.x;
    if (e < NE) {
        int d = dst[e];
        int p = atomicAdd(&cur[d], 1);
        csr_se[p] = make_int2(src[e], e);
    }
}

// ---------------- input prep + edge-count fused (independent work, one launch) ----------------
__global__ void k_cvt_x_count(const float* __restrict__ x, short* __restrict__ xb,
                              const int* __restrict__ dst, int* __restrict__ cnt) {
    int idx = blockIdx.x * 256 + threadIdx.x;
    if (idx < NE) atomicAdd(&cnt[dst[idx]], 1);
    if (idx >= NN * KP1) return;
    int i = idx / KP1, k = idx - i * KP1;
    xb[idx] = (k < DIN) ? f2bf(x[(size_t)i * DIN + k]) : (short)0;
}

// all weight transposes + bias concats + att block-diag expansion in ONE dispatch
__global__ void k_prep_w(const float* __restrict__ Wl1, const float* __restrict__ Wr1,
                         const float* __restrict__ Wres, const float* __restrict__ Wl2,
                         const float* __restrict__ Wr2, const float* __restrict__ Wout,
                         const float* __restrict__ bl1, const float* __restrict__ br1,
                         const float* __restrict__ bres, const float* __restrict__ bl2,
                         const float* __restrict__ br2,
                         const float* __restrict__ We1, const float* __restrict__ We2,
                         const float* __restrict__ att1, const float* __restrict__ att2,
                         short* __restrict__ Wt1, short* __restrict__ Wt2,
                         short* __restrict__ Wt3, float* __restrict__ bcat1,
                         float* __restrict__ bcat2,
                         short* __restrict__ WeT1, short* __restrict__ WeT2,
                         short* __restrict__ attB1, short* __restrict__ attB2) {
    int idx = blockIdx.x * 256 + threadIdx.x;
    if (idx < 384 * KP1) {
        int n = idx / KP1, k = idx - n * KP1;
        float v = 0.f;
        if (k < DIN) {
            const float* W = (n < 128) ? Wl1 : ((n < 256) ? Wr1 : Wres);
            v = W[(size_t)k * 128 + (n & 127)];
        }
        Wt1[idx] = f2bf(v);
        return;
    }
    idx -= 384 * KP1;
    if (idx < 256 * 128) {
        int n = idx >> 7, k = idx & 127;
        const float* W = (n < 128) ? Wl2 : Wr2;
        Wt2[idx] = f2bf(W[(size_t)k * 128 + (n & 127)]);
        return;
    }
    idx -= 256 * 128;
    if (idx < 128 * 128) {
        int n = idx >> 7, k = idx & 127;
        Wt3[idx] = f2bf(Wout[(size_t)k * 128 + n]);
        return;
    }
    idx -= 128 * 128;
    if (idx < 384) {
        bcat1[idx] = (idx < 128) ? bl1[idx] : ((idx < 256) ? br1[idx - 128] : bres[idx - 256]);
        return;
    }
    idx -= 384;
    if (idx < 256) {
        bcat2[idx] = (idx < 128) ? bl2[idx] : br2[idx - 128];
        return;
    }
    idx -= 256;
    if (idx < 128 * 32) {
        int n = idx >> 5, k = idx & 31;
        WeT1[idx] = (k < EDIM) ? f2bf(We1[(size_t)k * 128 + n]) : (short)0;
        return;
    }
    idx -= 128 * 32;
    if (idx < 128 * 32) {
        int n = idx >> 5, k = idx & 31;
        WeT2[idx] = (k < EDIM) ? f2bf(We2[(size_t)k * 128 + n]) : (short)0;
        return;
    }
    idx -= 128 * 32;
    if (idx < 16 * 128) {
        int n = idx >> 7, k = idx & 127;
        attB1[idx] = (n == (k >> 5)) ? f2bf(att1[k]) : (short)0;
        return;
    }
    idx -= 16 * 128;
    if (idx < 16 * 128) {
        int n = idx >> 7, k = idx & 127;
        attB2[idx] = (n == (k >> 5)) ? f2bf(att2[k]) : (short)0;
    }
}

// gather edge_attr rows into CSR order (f32 -> bf16, K pad 32) + contiguous dstp fill
__global__ __launch_bounds__(256) void k_gather_ea(const int2* __restrict__ csr_se,
                                                   const float* __restrict__ ea,
                                                   short* __restrict__ eaperm,
                                                   const int* __restrict__ off,
                                                   int* __restrict__ dstp) {
    int pos = blockIdx.x * 256 + threadIdx.x;
    if (pos < NN) {
        int b0 = off[pos], b1 = off[pos + 1];
        for (int p = b0; p < b1; ++p) dstp[p] = pos;
    }
    if (pos >= NE) return;
    int e = csr_se[pos].y;
    const float4* r = (const float4*)(ea + (size_t)e * EDIM);
    float4 v0 = r[0], v1 = r[1], v2 = r[2], v3 = r[3];
    uint4 w0 = make_uint4(pk2bf(v0.x, v0.y), pk2bf(v0.z, v0.w),
                          pk2bf(v1.x, v1.y), pk2bf(v1.z, v1.w));
    uint4 w1 = make_uint4(pk2bf(v2.x, v2.y), pk2bf(v2.z, v2.w),
                          pk2bf(v3.x, v3.y), pk2bf(v3.z, v3.w));
    uint4* o = (uint4*)(eaperm + (size_t)pos * 32);
    o[0] = w0; o[1] = w1;
    o[2] = make_uint4(0, 0, 0, 0);
    o[3] = make_uint4(0, 0, 0, 0);
}

// ---------------- bf16 MFMA GEMM: C[M x NS] = A[M x Kpad] @ Bt[NS x Kpad]^T + bias ----------------
template <bool BF16OUT>
__global__ __launch_bounds__(256) void k_mfma_gemm(const short* __restrict__ A,
                                                   const short* __restrict__ Bt,
                                                   const float* __restrict__ bias,
                                                   float* __restrict__ Cf,
                                                   short* __restrict__ Cb,
                                                   int M, int Kpad, int NS) {
    __shared__ short As[128 * 32];
    __shared__ short Bs[128 * 32];
    int t = threadIdx.x;
    int lane = t & 63, wid = t >> 6;
    int wm = (wid & 1) * 64, wn = (wid >> 1) * 64;
    int cl = lane & 15, quad = lane >> 4;
    int row0 = blockIdx.x * 128;
    int col0 = blockIdx.y * 128;

    f32x4 acc[4][4];
#pragma unroll
    for (int i = 0; i < 4; ++i)
#pragma unroll
        for (int j = 0; j < 4; ++j) acc[i][j] = (f32x4)0.f;

    for (int k0 = 0; k0 < Kpad; k0 += 32) {
#pragma unroll
        for (int r = 0; r < 2; ++r) {
            int c = t + r * 256;                     // chunk 0..511
            int m = c >> 2;
            int row = row0 + m; if (row >= M) row = M - 1;
            const char* ga = (const char*)A + ((size_t)row * Kpad + k0) * 2 + (c & 3) * 16;
            gload_lds16(ga, (char*)As + c * 16);
            int n = col0 + m;
            const char* gb = (const char*)Bt + ((size_t)n * Kpad + k0) * 2 + (c & 3) * 16;
            gload_lds16(gb, (char*)Bs + c * 16);
        }
        __syncthreads();

        short8 a[4], b[4];
#pragma unroll
        for (int mi = 0; mi < 4; ++mi)
            a[mi] = *(const short8*)&As[(wm + mi * 16 + cl) * 32 + quad * 8];
#pragma unroll
        for (int ni = 0; ni < 4; ++ni)
            b[ni] = *(const short8*)&Bs[(wn + ni * 16 + cl) * 32 + quad * 8];
#pragma unroll
        for (int mi = 0; mi < 4; ++mi)
#pragma unroll
            for (int ni = 0; ni < 4; ++ni)
                acc[mi][ni] = __builtin_amdgcn_mfma_f32_16x16x32_bf16(a[mi], b[ni], acc[mi][ni], 0, 0, 0);
        __syncthreads();
    }

#pragma unroll
    for (int mi = 0; mi < 4; ++mi)
#pragma unroll
        for (int ni = 0; ni < 4; ++ni) {
            int col = col0 + wn + ni * 16 + cl;
            float bv = bias[col];
#pragma unroll
            for (int r = 0; r < 4; ++r) {
                int row = row0 + wm + mi * 16 + quad * 4 + r;
                if (row < M) {
                    float v = acc[mi][ni][r] + bv;
                    if (BF16OUT) Cb[(size_t)row * NS + col] = f2bf(v);
                    else         Cf[(size_t)row * NS + col] = v;
                }
            }
        }
}

// ---------------- GEMM (M x 128 @ 128x128) with fused LayerNorm epilogue ----------------
__global__ __launch_bounds__(256) void k_gemm_ln(const short* __restrict__ A,
                                                 const short* __restrict__ Bt,
                                                 const float* __restrict__ bias,
                                                 const float* __restrict__ gamma,
                                                 const float* __restrict__ beta,
                                                 float* __restrict__ out, int M) {
    __shared__ short As[128 * 32];
    __shared__ short Bs[128 * 32];
    __shared__ float redS[128][2];
    int t = threadIdx.x;
    int lane = t & 63, wid = t >> 6;
    int wm = (wid & 1) * 64, wn = (wid >> 1) * 64;
    int cl = lane & 15, quad = lane >> 4;
    int row0 = blockIdx.x * 128;
    int wh = wid >> 1;                 // which 64-col half this wave owns

    f32x4 acc[4][4];
#pragma unroll
    for (int i = 0; i < 4; ++i)
#pragma unroll
        for (int j = 0; j < 4; ++j) acc[i][j] = (f32x4)0.f;

    for (int k0 = 0; k0 < 128; k0 += 32) {
#pragma unroll
        for (int r = 0; r < 2; ++r) {
            int c = t + r * 256;
            int m = c >> 2;
            int row = row0 + m; if (row >= M) row = M - 1;
            const char* ga = (const char*)A + ((size_t)row * 128 + k0) * 2 + (c & 3) * 16;
            gload_lds16(ga, (char*)As + c * 16);
            const char* gb = (const char*)Bt + ((size_t)m * 128 + k0) * 2 + (c & 3) * 16;
            gload_lds16(gb, (char*)Bs + c * 16);
        }
        __syncthreads();

        short8 a[4], b[4];
#pragma unroll
        for (int mi = 0; mi < 4; ++mi)
            a[mi] = *(const short8*)&As[(wm + mi * 16 + cl) * 32 + quad * 8];
#pragma unroll
        for (int ni = 0; ni < 4; ++ni)
            b[ni] = *(const short8*)&Bs[(wn + ni * 16 + cl) * 32 + quad * 8];
#pragma unroll
        for (int mi = 0; mi < 4; ++mi)
#pragma unroll
            for (int ni = 0; ni < 4; ++ni)
                acc[mi][ni] = __builtin_amdgcn_mfma_f32_16x16x32_bf16(a[mi], b[ni], acc[mi][ni], 0, 0, 0);
        __syncthreads();
    }

    // per-column params for this thread's 4 column slots
    float bv[4], gv[4], bev[4];
#pragma unroll
    for (int ni = 0; ni < 4; ++ni) {
        int col = wn + ni * 16 + cl;
        bv[ni] = bias[col]; gv[ni] = gamma[col]; bev[ni] = beta[col];
    }

    // ---- row sums (over this wave's 64 cols) ----
    float s[4][4];
#pragma unroll
    for (int mi = 0; mi < 4; ++mi)
#pragma unroll
        for (int r = 0; r < 4; ++r) {
            float v = (acc[mi][0][r] + bv[0]) + (acc[mi][1][r] + bv[1]) +
                      (acc[mi][2][r] + bv[2]) + (acc[mi][3][r] + bv[3]);
            v += __shfl_xor(v, 1, 64);
            v += __shfl_xor(v, 2, 64);
            v += __shfl_xor(v, 4, 64);
            v += __shfl_xor(v, 8, 64);
            s[mi][r] = v;
        }
    if (cl == 0) {
#pragma unroll
        for (int mi = 0; mi < 4; ++mi)
#pragma unroll
            for (int r = 0; r < 4; ++r)
                redS[wm + mi * 16 + quad * 4 + r][wh] = s[mi][r];
    }
    __syncthreads();
    float mean[4][4];
#pragma unroll
    for (int mi = 0; mi < 4; ++mi)
#pragma unroll
        for (int r = 0; r < 4; ++r) {
            int rl = wm + mi * 16 + quad * 4 + r;
            mean[mi][r] = (redS[rl][0] + redS[rl][1]) * (1.f / 128.f);
        }
    __syncthreads();

    // ---- row variances ----
#pragma unroll
    for (int mi = 0; mi < 4; ++mi)
#pragma unroll
        for (int r = 0; r < 4; ++r) {
            float q = 0.f;
#pragma unroll
            for (int ni = 0; ni < 4; ++ni) {
                float d = acc[mi][ni][r] + bv[ni] - mean[mi][r];
                q = fmaf(d, d, q);
            }
            q += __shfl_xor(q, 1, 64);
            q += __shfl_xor(q, 2, 64);
            q += __shfl_xor(q, 4, 64);
            q += __shfl_xor(q, 8, 64);
            s[mi][r] = q;
        }
    if (cl == 0) {
#pragma unroll
        for (int mi = 0; mi < 4; ++mi)
#pragma unroll
            for (int r = 0; r < 4; ++r)
                redS[wm + mi * 16 + quad * 4 + r][wh] = s[mi][r];
    }
    __syncthreads();

#pragma unroll
    for (int mi = 0; mi < 4; ++mi)
#pragma unroll
        for (int r = 0; r < 4; ++r) {
            int rl = wm + mi * 16 + quad * 4 + r;
            int row = row0 + rl;
            if (row < M) {
                float rstd = rsqrtf((redS[rl][0] + redS[rl][1]) * (1.f / 128.f) + 1e-5f);
#pragma unroll
                for (int ni = 0; ni < 4; ++ni) {
                    int col = wn + ni * 16 + cl;
                    float d = acc[mi][ni][r] + bv[ni] - mean[mi][r];
                    out[(size_t)row * 128 + col] = fmaf(d * rstd, gv[ni], bev[ni]);
                }
            }
        }
}

// ---------------- edge score kernel (eaperm staging, 512 thr) ----------------
// Per block: 128 CSR-ordered edges, 8 waves.
// Phase 1: ee[128x128] = eaperm_tile @ WeT^T via MFMA, fragments DIRECT from
//          global (eaperm rows coalesced 1KB/wave; WeT 8KB L1-resident).
// Phase 2: g = leaky(ee + xl[src] + xr[dst]) -> Gs (lane=f: coalesced row reads).
// Phase 3: S[128x16] = g @ attB^T (attB block-diag; Ab/Gs stride 136).
// Phase 4: pe[e,h] = exp(S).
template <int STRIDE>
__global__ __launch_bounds__(512) void k_edge_score(const short* __restrict__ eaperm,
                                                    const short* __restrict__ WeT,
                                                    const short* __restrict__ attB,
                                                    const int2* __restrict__ csr_se,
                                                    const int* __restrict__ dstp,
                                                    const short* __restrict__ C,
                                                    float* __restrict__ pe) {
    __shared__ short Gs[128 * 136];
    __shared__ short Ab[16 * 136];
    __shared__ int sS[128], sD[128];
    int t = threadIdx.x;
    int lane = t & 63, wid = t >> 6;          // 8 waves
    int wm2 = (wid & 1) * 64;                 // edge half
    int wn2 = (wid >> 1) * 32;                // f quarter
    int cl = lane & 15, quad = lane >> 4;
    long e0 = (long)blockIdx.x * 128;

    if (t < 128) {
        long ep = e0 + t; if (ep >= NE) ep = NE - 1;
        sS[t] = csr_se[ep].x;
        sD[t] = dstp[ep];
    } else if (t < 384) {
        int u = t - 128;                      // 0..255 -> 16 rows x 16 chunks of 8 shorts
        int rr = u >> 4, cc = (u & 15) * 8;
        *(short8*)&Ab[rr * 136 + cc] = *(const short8*)&attB[rr * 128 + cc];
    }

    // ---- phase 1: fragments direct from global, 8 MFMAs ----
    short8 a[4], b[2];
#pragma unroll
    for (int mi = 0; mi < 4; ++mi) {
        long e = e0 + wm2 + mi * 16 + cl; if (e >= NE) e = NE - 1;
        a[mi] = *(const short8*)&eaperm[e * 32 + quad * 8];
    }
#pragma unroll
    for (int ni = 0; ni < 2; ++ni)
        b[ni] = *(const short8*)&WeT[(size_t)(wn2 + ni * 16 + cl) * 32 + quad * 8];

    f32x4 acc[4][2];
#pragma unroll
    for (int i = 0; i < 4; ++i) { acc[i][0] = (f32x4)0.f; acc[i][1] = (f32x4)0.f; }
#pragma unroll
    for (int mi = 0; mi < 4; ++mi)
#pragma unroll
        for (int ni = 0; ni < 2; ++ni)
            acc[mi][ni] = __builtin_amdgcn_mfma_f32_16x16x32_bf16(a[mi], b[ni], acc[mi][ni], 0, 0, 0);
    __syncthreads();   // sS/sD/Ab ready

    // ---- phase 2: g = leaky(ee + xl + xr) -> Gs (coalesced: lanes = consecutive f) ----
#pragma unroll
    for (int mi = 0; mi < 4; ++mi) {
#pragma unroll
        for (int r = 0; r < 4; ++r) {
            int eloc = wm2 + mi * 16 + quad * 4 + r;
            const short* xlr = C + (size_t)sS[eloc] * STRIDE;
            const short* xrr = C + (size_t)sD[eloc] * STRIDE + 128;
            int f0 = wn2 + cl, f1 = wn2 + 16 + cl;
            float xl0 = bf2f(xlr[f0]), xr0 = bf2f(xrr[f0]);
            float xl1 = bf2f(xlr[f1]), xr1 = bf2f(xrr[f1]);
            float g0 = acc[mi][0][r] + xl0 + xr0;
            float g1 = acc[mi][1][r] + xl1 + xr1;
            g0 = fmaxf(g0, 0.2f * g0);
            g1 = fmaxf(g1, 0.2f * g1);
            Gs[eloc * 136 + f0] = f2bf(g0);
            Gs[eloc * 136 + f1] = f2bf(g1);
        }
    }
    __syncthreads();

    // ---- phase 3: scores = g @ attB^T (16 edges per wave, 4 MFMAs) ----
    f32x4 sacc = (f32x4)0.f;
    int em0 = wid * 16;
#pragma unroll
    for (int ks = 0; ks < 4; ++ks) {
        short8 ag = *(const short8*)&Gs[(em0 + cl) * 136 + ks * 32 + quad * 8];
        short8 bg = *(const short8*)&Ab[cl * 136 + ks * 32 + quad * 8];
        sacc = __builtin_amdgcn_mfma_f32_16x16x32_bf16(ag, bg, sacc, 0, 0, 0);
    }

    // ---- phase 4: exp + store (D layout: col=cl (head), row=quad*4+r (edge)) ----
    if (cl < 4) {
#pragma unroll
        for (int r = 0; r < 4; ++r) {
            long epos = e0 + em0 + quad * 4 + r;
            if (epos < NE) pe[epos * 4 + cl] = __expf(sacc[r]);
        }
    }
}

// ---------------- slim softmax-aggregate + epilogue (4-edge ILP) ----------------
// ONE WAVE PER 2-NODE CHUNK (grid 6250 x 4 waves). Per iteration: 4 edges in
// flight — next-4 csr/pe prefetch overlaps current-4 xl gathers + FMAs
// (latency-bound chain per round-11 counters: VALUBusy 44%, HBM 22%).
// All arrays fully unrolled -> static register indexing.
template <int STRIDE>
__global__ __launch_bounds__(256) void k_fused_agg(const int* __restrict__ off,
                                                   const int2* __restrict__ csr_se,
                                                   const float* __restrict__ pe,
                                                   const short* __restrict__ C,
                                                   const short* __restrict__ resid, int rstride,
                                                   const float* __restrict__ bias,
                                                   const float* __restrict__ gamma,
                                                   const float* __restrict__ beta,
                                                   short* __restrict__ outb) {
    int t = threadIdx.x;
    int w = t >> 6, l = t & 63;
    int f0 = (l >> 4) * 32 + (l & 15) * 2;   // even feature; f1 = f0+1 (same head)
    int fp = f0 >> 1;
    int hd = l >> 4;                          // head index

    float2 bs2 = ((const float2*)bias)[fp];
    float2 gv = ((const float2*)gamma)[fp];
    float2 bev = ((const float2*)beta)[fp];

    int n0 = (blockIdx.x * 4 + w) * 2;
    int nend = n0 + 2; if (nend > NN) nend = NN;

    for (int i = n0; i < nend; ++i) {
        unsigned rp = *(const unsigned*)&resid[(size_t)i * rstride + f0];  // early issue
        int b0 = off[i], b1 = off[i + 1];

        float lr[4] = {0.f, 0.f, 0.f, 0.f};
        float a0[4] = {0.f, 0.f, 0.f, 0.f};
        float a1[4] = {0.f, 0.f, 0.f, 0.f};
        int pos = b0;
        int sC[4] = {0, 0, 0, 0};
        float pC[4] = {0.f, 0.f, 0.f, 0.f};
        bool have = (pos + 4 <= b1);
        if (have) {
#pragma unroll
            for (int j = 0; j < 4; ++j) {
                int2 se = csr_se[pos + j];
                sC[j] = se.x;
                pC[j] = pe[(size_t)(pos + j) * 4 + hd];
            }
        }
        while (have) {
            bool haven = (pos + 8 <= b1);
            int nS[4] = {0, 0, 0, 0};
            float nP[4] = {0.f, 0.f, 0.f, 0.f};
            if (haven) {
#pragma unroll
                for (int j = 0; j < 4; ++j) {
                    int2 se = csr_se[pos + 4 + j];
                    nS[j] = se.x;
                    nP[j] = pe[(size_t)(pos + 4 + j) * 4 + hd];
                }
            }
            unsigned xl[4];
#pragma unroll
            for (int j = 0; j < 4; ++j)
                xl[j] = *(const unsigned*)&C[(size_t)sC[j] * STRIDE + f0];
#pragma unroll
            for (int j = 0; j < 4; ++j) {
                lr[j] += pC[j];
                a0[j] = fmaf(pC[j], bflo(xl[j]), a0[j]);
                a1[j] = fmaf(pC[j], bfhi(xl[j]), a1[j]);
            }
            pos += 4;
#pragma unroll
            for (int j = 0; j < 4; ++j) { sC[j] = nS[j]; pC[j] = nP[j]; }
            have = haven;
        }
        for (; pos < b1; ++pos) {             // tail 0..3 edges
            int2 se = csr_se[pos];
            float p1 = pe[(size_t)pos * 4 + hd];
            unsigned xlv = *(const unsigned*)&C[(size_t)se.x * STRIDE + f0];
            lr[0] += p1;
            a0[0] = fmaf(p1, bflo(xlv), a0[0]);
            a1[0] = fmaf(p1, bfhi(xlv), a1[0]);
        }
        float l_run = (lr[0] + lr[1]) + (lr[2] + lr[3]);
        float acc0 = (a0[0] + a0[1]) + (a0[2] + a0[3]);
        float acc1 = (a1[0] + a1[1]) + (a1[2] + a1[3]);

        float inv = 1.f / (l_run + 1e-16f);
        float o0 = fmaf(acc0, inv, bs2.x);
        float o1 = fmaf(acc1, inv, bs2.y);
        o0 = o0 > 0.f ? o0 : (__expf(o0) - 1.f);            // ELU
        o1 = o1 > 0.f ? o1 : (__expf(o1) - 1.f);
        float v0 = o0 + bflo(rp), v1 = o1 + bfhi(rp);       // + residual
        // in-wave LayerNorm over 128 features (2 per lane)
        float s = v0 + v1;
#pragma unroll
        for (int o = 32; o > 0; o >>= 1) s += __shfl_xor(s, o, 64);
        float mean = s * (1.f / 128.f);
        float d0 = v0 - mean, d1 = v1 - mean;
        float q = fmaf(d0, d0, d1 * d1);
#pragma unroll
        for (int o = 32; o > 0; o >>= 1) q += __shfl_xor(q, o, 64);
        float rstd = rsqrtf(q * (1.f / 128.f) + 1e-5f);
        float r0 = fmaf(d0 * rstd, gv.x, bev.x);
        float r1 = fmaf(d1 * rstd, gv.y, bev.y);
        unsigned op = (unsigned)(unsigned short)f2bf(r0) |
                      (((unsigned)(unsigned short)f2bf(r1)) << 16);
        *(unsigned*)&outb[(size_t)i * 128 + f0] = op;
    }
}

extern "C" void kernel_launch(void* const* d_in, const int* in_sizes, int n_in,
                              void* d_out, int out_size, void* d_ws, size_t ws_size,
                              hipStream_t stream) {
    (void)in_sizes; (void)n_in; (void)out_size; (void)ws_size;
    const float* x     = (const float*)d_in[0];
    const float* ea    = (const float*)d_in[1];
    const float* Wl1   = (const float*)d_in[2];
    const float* bl1   = (const float*)d_in[3];
    const float* Wr1   = (const float*)d_in[4];
    const float* br1   = (const float*)d_in[5];
    const float* We1   = (const float*)d_in[6];
    const float* att1  = (const float*)d_in[7];
    const float* bias1 = (const float*)d_in[8];
    const float* Wl2   = (const float*)d_in[9];
    const float* bl2   = (const float*)d_in[10];
    const float* Wr2   = (const float*)d_in[11];
    const float* br2   = (const float*)d_in[12];
    const float* We2   = (const float*)d_in[13];
    const float* att2  = (const float*)d_in[14];
    const float* bias2 = (const float*)d_in[15];
    const float* Wres  = (const float*)d_in[16];
    const float* bres  = (const float*)d_in[17];
    const float* Wout  = (const float*)d_in[18];
    const float* bout  = (const float*)d_in[19];
    const float* g1    = (const float*)d_in[20];
    const float* bn1   = (const float*)d_in[21];
    const float* g2    = (const float*)d_in[22];
    const float* bn2   = (const float*)d_in[23];
    const float* go    = (const float*)d_in[24];
    const float* bo    = (const float*)d_in[25];
    const int*   ei    = (const int*)d_in[26];
    const int* srcv = ei;
    const int* dstv = ei + NE;
    float* outp = (float*)d_out;

    char* p = (char*)d_ws;
    auto carve = [&](size_t bytes) {
        char* r = p;
        p += (bytes + 255) & ~(size_t)255;
        return r;
    };
    short* xb    = (short*)carve((size_t)NN * KP1 * 2);
    short* Wt1   = (short*)carve((size_t)384 * KP1 * 2);
    short* Wt2   = (short*)carve((size_t)256 * 128 * 2);
    short* Wt3   = (short*)carve((size_t)128 * 128 * 2);
    short* WeT1  = (short*)carve((size_t)128 * 32 * 2);
    short* WeT2  = (short*)carve((size_t)128 * 32 * 2);
    short* attB1 = (short*)carve((size_t)16 * 128 * 2);
    short* attB2 = (short*)carve((size_t)16 * 128 * 2);
    float* bcat1 = (float*)carve(384 * 4);
    float* bcat2 = (float*)carve(256 * 4);
    short* C1    = (short*)carve((size_t)NN * 384 * 2);   // bf16 [xl|xr|res]
    short* h1b   = (short*)carve((size_t)NN * 128 * 2);
    short* h2b   = (short*)carve((size_t)NN * 128 * 2);
    int* off     = (int*)carve((size_t)(NN + 1) * 4);
    int* cur     = (int*)carve((size_t)NN * 4);
    int* bsum    = (int*)carve(256 * 4);
    int2* csr_se = (int2*)carve((size_t)NE * 8);          // {src, edge_id} per CSR position
    int* dstp    = (int*)carve((size_t)NE * 4);           // filled contiguously from off
    short* eaperm = (short*)carve((size_t)NE * 32 * 2);   // 32 MB, CSR-ordered bf16 ea (K pad 32)
    float* pe    = (float*)carve((size_t)NE * 4 * 4);     // 8 MB, exp(score) per edge x head

    short* C2 = C1;                                  // stride 256, reuse after layer 1

    const int NB = (NN + 255) / 256;                 // 196

    // ---- CSR build + input prep (count fused into cvt_x) ----
    hipMemsetAsync(cur, 0, (size_t)NN * 4, stream);
    k_cvt_x_count<<<((size_t)NN * KP1 + 255) / 256, 256, 0, stream>>>(x, xb, dstv, cur);
    k_scan1<<<NB, 256, 0, stream>>>(cur, off, bsum);
    k_scan2<<<1, 256, 0, stream>>>(bsum, NB);
    k_scan3c<<<(NN + 256) / 256, 256, 0, stream>>>(off, bsum, cur);
    k_scatter<<<(NE + 255) / 256, 256, 0, stream>>>(srcv, dstv, cur, csr_se);

    // ---- prep ----
    int prep_total = 384 * KP1 + 256 * 128 + 128 * 128 + 384 + 256 + 2 * 128 * 32 + 2 * 16 * 128;
    k_prep_w<<<(prep_total + 255) / 256, 256, 0, stream>>>(Wl1, Wr1, Wres, Wl2, Wr2, Wout,
                                                           bl1, br1, bres, bl2, br2,
                                                           We1, We2, att1, att2,
                                                           Wt1, Wt2, Wt3, bcat1, bcat2,
                                                           WeT1, WeT2, attB1, attB2);
    k_gather_ea<<<(NE + 255) / 256, 256, 0, stream>>>(csr_se, ea, eaperm, off, dstp);

    int mb  = (NN + 127) / 128;                      // 391
    int ebk = (NE + 127) / 128;                      // 3907
    int gagg = NN / 8;                               // 6250 blocks (4 waves x 2 nodes)

    // ---- layer 1 ----
    k_mfma_gemm<true><<<dim3(mb, 3), 256, 0, stream>>>(xb, Wt1, bcat1, nullptr, C1, NN, KP1, 384);
    k_edge_score<384><<<ebk, 512, 0, stream>>>(eaperm, WeT1, attB1, csr_se, dstp, C1, pe);
    k_fused_agg<384><<<gagg, 256, 0, stream>>>(off, csr_se, pe, C1,
                                               C1 + 256, 384, bias1, g1, bn1, h1b);
    // ---- layer 2 ----
    k_mfma_gemm<true><<<dim3(mb, 2), 256, 0, stream>>>(h1b, Wt2, bcat2, nullptr, C2, NN, 128, 256);
    k_edge_score<256><<<ebk, 512, 0, stream>>>(eaperm, WeT2, attB2, csr_se, dstp, C2, pe);
    k_fused_agg<256><<<gagg, 256, 0, stream>>>(off, csr_se, pe, C2,
                                               h1b, 128, bias2, g2, bn2, h2b);
    // ---- output: GEMM + fused LN ----
    k_gemm_ln<<<mb, 256, 0, stream>>>(h2b, Wt3, bout, go, bo, outp, NN);
}

// Round 13
// 439.671 us; speedup vs baseline: 1.1106x; 1.0471x over previous
//
#include <hip/hip_runtime.h>
#include <hip/hip_bf16.h>
#include <math.h>
#include <stdint.h>

#define NN 50000
#define NE 500000
#define DIN 264
#define KP1 288      // DIN padded to multiple of 32
#define HID 128
#define EDIM 16
#define CVT_CH 36    // KP1/8 chunks per row

typedef __attribute__((ext_vector_type(8))) short short8;
typedef __attribute__((ext_vector_type(4))) float f32x4;

__device__ __forceinline__ short f2bf(float v) {
    union { float f; unsigned u; } x; x.f = v;
    unsigned r = x.u + 0x7fff + ((x.u >> 16) & 1);
    return (short)(r >> 16);
}
__device__ __forceinline__ float bf2f(short v) {
    union { float f; unsigned u; } x;
    x.u = ((unsigned)(unsigned short)v) << 16;
    return x.f;
}
// unpack two bf16 packed in a dword
__device__ __forceinline__ float bflo(unsigned u) {
    union { float f; unsigned u; } x; x.u = u << 16; return x.f;
}
__device__ __forceinline__ float bfhi(unsigned u) {
    union { float f; unsigned u; } x; x.u = u & 0xffff0000u; return x.f;
}
__device__ __forceinline__ unsigned pk2bf(float a, float b) {
    return (unsigned)(unsigned short)f2bf(a) | ((unsigned)(unsigned short)f2bf(b) << 16);
}

__device__ __forceinline__ void gload_lds16(const void* g, void* l) {
    __builtin_amdgcn_global_load_lds(
        (const __attribute__((address_space(1))) unsigned int*)g,
        (__attribute__((address_space(3))) unsigned int*)l, 16, 0, 0);
}

// ---------------- CSR build (dst -> in-edges) ----------------
__global__ __launch_bounds__(256) void k_scan1(const int* __restrict__ cnt,
                                               int* __restrict__ off, int* __restrict__ bsum) {
    __shared__ int buf[256];
    int b = blockIdx.x, t = threadIdx.x;
    int i = b * 256 + t;
    int v = (i < NN) ? cnt[i] : 0;
    buf[t] = v; __syncthreads();
    for (int s = 1; s < 256; s <<= 1) {
        int u = (t >= s) ? buf[t - s] : 0; __syncthreads();
        buf[t] += u; __syncthreads();
    }
    if (i < NN) off[i + 1] = buf[t];
    if (t == 255) bsum[b] = buf[255];
}

__global__ void k_scan2(int* __restrict__ bsum, int nb) {
    __shared__ int buf[256];
    int t = threadIdx.x;
    int o = (t < nb) ? bsum[t] : 0;
    buf[t] = o; __syncthreads();
    for (int s = 1; s < 256; s <<= 1) {
        int u = (t >= s) ? buf[t - s] : 0; __syncthreads();
        buf[t] += u; __syncthreads();
    }
    if (t < nb) bsum[t] = buf[t] - o;   // exclusive
}

// finalize offsets AND copy to cur in one pass
__global__ void k_scan3c(int* __restrict__ off, const int* __restrict__ bsum,
                         int* __restrict__ cur) {
    int j = blockIdx.x * 256 + threadIdx.x;   // 0..NN
    if (j > NN) return;
    int v = (j == 0) ? 0 : off[j] + bsum[(j - 1) >> 8];
    off[j] = v;
    if (j < NN) cur[j] = v;
}

// ONE 8B scattered write per edge (1 dirty line, vs 3 for split arrays)
__global__ void k_scatter(const int* __restrict__ src, const int* __restrict__ dst,
                          int* __restrict__ cur, int2* __restrict__ csr_se) {
    int e = blockIdx.x * blockDim.x + threadIdx.x;
    if (e < NE) {
        int d = dst[e];
        int p = atomicAdd(&cur[d], 1);
        csr_se[p] = make_int2(src[e], e);
    }
}

// ---------------- input prep (8-wide vectorized) + edge-count fused ----------------
// Each thread converts 8 floats -> short8 (two float4 reads, one 16B write;
// DIN=264 and KP1=288 both divisible by 8 so chunks are full-or-zero).
// Threads with idx < NE also do the degree-count atomic (hides under stream).
__global__ __launch_bounds__(256) void k_cvt_x_count(const float* __restrict__ x,
                                                     short* __restrict__ xb,
                                                     const int* __restrict__ dst,
                                                     int* __restrict__ cnt) {
    int idx = blockIdx.x * 256 + threadIdx.x;
    if (idx < NE) atomicAdd(&cnt[dst[idx]], 1);
    if (idx >= NN * CVT_CH) return;
    int i = idx / CVT_CH, c = idx - i * CVT_CH;
    int k0 = c * 8;
    short8 v;
    if (k0 < DIN) {                           // full 8-chunk (264 % 8 == 0)
        const float4* r = (const float4*)(x + (size_t)i * DIN + k0);
        float4 v0 = r[0], v1 = r[1];
        v[0] = f2bf(v0.x); v[1] = f2bf(v0.y); v[2] = f2bf(v0.z); v[3] = f2bf(v0.w);
        v[4] = f2bf(v1.x); v[5] = f2bf(v1.y); v[6] = f2bf(v1.z); v[7] = f2bf(v1.w);
    } else {
        v = (short8)0;                        // K padding 264..287
    }
    *(short8*)&xb[(size_t)i * KP1 + k0] = v;
}

// all weight transposes + bias concats + att block-diag expansion in ONE dispatch
__global__ void k_prep_w(const float* __restrict__ Wl1, const float* __restrict__ Wr1,
                         const float* __restrict__ Wres, const float* __restrict__ Wl2,
                         const float* __restrict__ Wr2, const float* __restrict__ Wout,
                         const float* __restrict__ bl1, const float* __restrict__ br1,
                         const float* __restrict__ bres, const float* __restrict__ bl2,
                         const float* __restrict__ br2,
                         const float* __restrict__ We1, const float* __restrict__ We2,
                         const float* __restrict__ att1, const float* __restrict__ att2,
                         short* __restrict__ Wt1, short* __restrict__ Wt2,
                         short* __restrict__ Wt3, float* __restrict__ bcat1,
                         float* __restrict__ bcat2,
                         short* __restrict__ WeT1, short* __restrict__ WeT2,
                         short* __restrict__ attB1, short* __restrict__ attB2) {
    int idx = blockIdx.x * 256 + threadIdx.x;
    if (idx < 384 * KP1) {
        int n = idx / KP1, k = idx - n * KP1;
        float v = 0.f;
        if (k < DIN) {
            const float* W = (n < 128) ? Wl1 : ((n < 256) ? Wr1 : Wres);
            v = W[(size_t)k * 128 + (n & 127)];
        }
        Wt1[idx] = f2bf(v);
        return;
    }
    idx -= 384 * KP1;
    if (idx < 256 * 128) {
        int n = idx >> 7, k = idx & 127;
        const float* W = (n < 128) ? Wl2 : Wr2;
        Wt2[idx] = f2bf(W[(size_t)k * 128 + (n & 127)]);
        return;
    }
    idx -= 256 * 128;
    if (idx < 128 * 128) {
        int n = idx >> 7, k = idx & 127;
        Wt3[idx] = f2bf(Wout[(size_t)k * 128 + n]);
        return;
    }
    idx -= 128 * 128;
    if (idx < 384) {
        bcat1[idx] = (idx < 128) ? bl1[idx] : ((idx < 256) ? br1[idx - 128] : bres[idx - 256]);
        return;
    }
    idx -= 384;
    if (idx < 256) {
        bcat2[idx] = (idx < 128) ? bl2[idx] : br2[idx - 128];
        return;
    }
    idx -= 256;
    if (idx < 128 * 32) {
        int n = idx >> 5, k = idx & 31;
        WeT1[idx] = (k < EDIM) ? f2bf(We1[(size_t)k * 128 + n]) : (short)0;
        return;
    }
    idx -= 128 * 32;
    if (idx < 128 * 32) {
        int n = idx >> 5, k = idx & 31;
        WeT2[idx] = (k < EDIM) ? f2bf(We2[(size_t)k * 128 + n]) : (short)0;
        return;
    }
    idx -= 128 * 32;
    if (idx < 16 * 128) {
        int n = idx >> 7, k = idx & 127;
        attB1[idx] = (n == (k >> 5)) ? f2bf(att1[k]) : (short)0;
        return;
    }
    idx -= 16 * 128;
    if (idx < 16 * 128) {
        int n = idx >> 7, k = idx & 127;
        attB2[idx] = (n == (k >> 5)) ? f2bf(att2[k]) : (short)0;
    }
}

// gather edge_attr rows into CSR order (f32 -> bf16, K pad 32) + contiguous dstp fill
__global__ __launch_bounds__(256) void k_gather_ea(const int2* __restrict__ csr_se,
                                                   const float* __restrict__ ea,
                                                   short* __restrict__ eaperm,
                                                   const int* __restrict__ off,
                                                   int* __restrict__ dstp) {
    int pos = blockIdx.x * 256 + threadIdx.x;
    if (pos < NN) {
        int b0 = off[pos], b1 = off[pos + 1];
        for (int p = b0; p < b1; ++p) dstp[p] = pos;
    }
    if (pos >= NE) return;
    int e = csr_se[pos].y;
    const float4* r = (const float4*)(ea + (size_t)e * EDIM);
    float4 v0 = r[0], v1 = r[1], v2 = r[2], v3 = r[3];
    uint4 w0 = make_uint4(pk2bf(v0.x, v0.y), pk2bf(v0.z, v0.w),
                          pk2bf(v1.x, v1.y), pk2bf(v1.z, v1.w));
    uint4 w1 = make_uint4(pk2bf(v2.x, v2.y), pk2bf(v2.z, v2.w),
                          pk2bf(v3.x, v3.y), pk2bf(v3.z, v3.w));
    uint4* o = (uint4*)(eaperm + (size_t)pos * 32);
    o[0] = w0; o[1] = w1;
    o[2] = make_uint4(0, 0, 0, 0);
    o[3] = make_uint4(0, 0, 0, 0);
}

// ---------------- bf16 MFMA GEMM: C[M x NS] = A[M x Kpad] @ Bt[NS x Kpad]^T + bias ----------------
template <bool BF16OUT>
__global__ __launch_bounds__(256) void k_mfma_gemm(const short* __restrict__ A,
                                                   const short* __restrict__ Bt,
                                                   const float* __restrict__ bias,
                                                   float* __restrict__ Cf,
                                                   short* __restrict__ Cb,
                                                   int M, int Kpad, int NS) {
    __shared__ short As[128 * 32];
    __shared__ short Bs[128 * 32];
    int t = threadIdx.x;
    int lane = t & 63, wid = t >> 6;
    int wm = (wid & 1) * 64, wn = (wid >> 1) * 64;
    int cl = lane & 15, quad = lane >> 4;
    int row0 = blockIdx.x * 128;
    int col0 = blockIdx.y * 128;

    f32x4 acc[4][4];
#pragma unroll
    for (int i = 0; i < 4; ++i)
#pragma unroll
        for (int j = 0; j < 4; ++j) acc[i][j] = (f32x4)0.f;

    for (int k0 = 0; k0 < Kpad; k0 += 32) {
#pragma unroll
        for (int r = 0; r < 2; ++r) {
            int c = t + r * 256;                     // chunk 0..511
            int m = c >> 2;
            int row = row0 + m; if (row >= M) row = M - 1;
            const char* ga = (const char*)A + ((size_t)row * Kpad + k0) * 2 + (c & 3) * 16;
            gload_lds16(ga, (char*)As + c * 16);
            int n = col0 + m;
            const char* gb = (const char*)Bt + ((size_t)n * Kpad + k0) * 2 + (c & 3) * 16;
            gload_lds16(gb, (char*)Bs + c * 16);
        }
        __syncthreads();

        short8 a[4], b[4];
#pragma unroll
        for (int mi = 0; mi < 4; ++mi)
            a[mi] = *(const short8*)&As[(wm + mi * 16 + cl) * 32 + quad * 8];
#pragma unroll
        for (int ni = 0; ni < 4; ++ni)
            b[ni] = *(const short8*)&Bs[(wn + ni * 16 + cl) * 32 + quad * 8];
#pragma unroll
        for (int mi = 0; mi < 4; ++mi)
#pragma unroll
            for (int ni = 0; ni < 4; ++ni)
                acc[mi][ni] = __builtin_amdgcn_mfma_f32_16x16x32_bf16(a[mi], b[ni], acc[mi][ni], 0, 0, 0);
        __syncthreads();
    }

#pragma unroll
    for (int mi = 0; mi < 4; ++mi)
#pragma unroll
        for (int ni = 0; ni < 4; ++ni) {
            int col = col0 + wn + ni * 16 + cl;
            float bv = bias[col];
#pragma unroll
            for (int r = 0; r < 4; ++r) {
                int row = row0 + wm + mi * 16 + quad * 4 + r;
                if (row < M) {
                    float v = acc[mi][ni][r] + bv;
                    if (BF16OUT) Cb[(size_t)row * NS + col] = f2bf(v);
                    else         Cf[(size_t)row * NS + col] = v;
                }
            }
        }
}

// ---------------- GEMM (M x 128 @ 128x128) with fused LayerNorm epilogue ----------------
__global__ __launch_bounds__(256) void k_gemm_ln(const short* __restrict__ A,
                                                 const short* __restrict__ Bt,
                                                 const float* __restrict__ bias,
                                                 const float* __restrict__ gamma,
                                                 const float* __restrict__ beta,
                                                 float* __restrict__ out, int M) {
    __shared__ short As[128 * 32];
    __shared__ short Bs[128 * 32];
    __shared__ float redS[128][2];
    int t = threadIdx.x;
    int lane = t & 63, wid = t >> 6;
    int wm = (wid & 1) * 64, wn = (wid >> 1) * 64;
    int cl = lane & 15, quad = lane >> 4;
    int row0 = blockIdx.x * 128;
    int wh = wid >> 1;                 // which 64-col half this wave owns

    f32x4 acc[4][4];
#pragma unroll
    for (int i = 0; i < 4; ++i)
#pragma unroll
        for (int j = 0; j < 4; ++j) acc[i][j] = (f32x4)0.f;

    for (int k0 = 0; k0 < 128; k0 += 32) {
#pragma unroll
        for (int r = 0; r < 2; ++r) {
            int c = t + r * 256;
            int m = c >> 2;
            int row = row0 + m; if (row >= M) row = M - 1;
            const char* ga = (const char*)A + ((size_t)row * 128 + k0) * 2 + (c & 3) * 16;
            gload_lds16(ga, (char*)As + c * 16);
            const char* gb = (const char*)Bt + ((size_t)m * 128 + k0) * 2 + (c & 3) * 16;
            gload_lds16(gb, (char*)Bs + c * 16);
        }
        __syncthreads();

        short8 a[4], b[4];
#pragma unroll
        for (int mi = 0; mi < 4; ++mi)
            a[mi] = *(const short8*)&As[(wm + mi * 16 + cl) * 32 + quad * 8];
#pragma unroll
        for (int ni = 0; ni < 4; ++ni)
            b[ni] = *(const short8*)&Bs[(wn + ni * 16 + cl) * 32 + quad * 8];
#pragma unroll
        for (int mi = 0; mi < 4; ++mi)
#pragma unroll
            for (int ni = 0; ni < 4; ++ni)
                acc[mi][ni] = __builtin_amdgcn_mfma_f32_16x16x32_bf16(a[mi], b[ni], acc[mi][ni], 0, 0, 0);
        __syncthreads();
    }

    // per-column params for this thread's 4 column slots
    float bv[4], gv[4], bev[4];
#pragma unroll
    for (int ni = 0; ni < 4; ++ni) {
        int col = wn + ni * 16 + cl;
        bv[ni] = bias[col]; gv[ni] = gamma[col]; bev[ni] = beta[col];
    }

    // ---- row sums (over this wave's 64 cols) ----
    float s[4][4];
#pragma unroll
    for (int mi = 0; mi < 4; ++mi)
#pragma unroll
        for (int r = 0; r < 4; ++r) {
            float v = (acc[mi][0][r] + bv[0]) + (acc[mi][1][r] + bv[1]) +
                      (acc[mi][2][r] + bv[2]) + (acc[mi][3][r] + bv[3]);
            v += __shfl_xor(v, 1, 64);
            v += __shfl_xor(v, 2, 64);
            v += __shfl_xor(v, 4, 64);
            v += __shfl_xor(v, 8, 64);
            s[mi][r] = v;
        }
    if (cl == 0) {
#pragma unroll
        for (int mi = 0; mi < 4; ++mi)
#pragma unroll
            for (int r = 0; r < 4; ++r)
                redS[wm + mi * 16 + quad * 4 + r][wh] = s[mi][r];
    }
    __syncthreads();
    float mean[4][4];
#pragma unroll
    for (int mi = 0; mi < 4; ++mi)
#pragma unroll
        for (int r = 0; r < 4; ++r) {
            int rl = wm + mi * 16 + quad * 4 + r;
            mean[mi][r] = (redS[rl][0] + redS[rl][1]) * (1.f / 128.f);
        }
    __syncthreads();

    // ---- row variances ----
#pragma unroll
    for (int mi = 0; mi < 4; ++mi)
#pragma unroll
        for (int r = 0; r < 4; ++r) {
            float q = 0.f;
#pragma unroll
            for (int ni = 0; ni < 4; ++ni) {
                float d = acc[mi][ni][r] + bv[ni] - mean[mi][r];
                q = fmaf(d, d, q);
            }
            q += __shfl_xor(q, 1, 64);
            q += __shfl_xor(q, 2, 64);
            q += __shfl_xor(q, 4, 64);
            q += __shfl_xor(q, 8, 64);
            s[mi][r] = q;
        }
    if (cl == 0) {
#pragma unroll
        for (int mi = 0; mi < 4; ++mi)
#pragma unroll
            for (int r = 0; r < 4; ++r)
                redS[wm + mi * 16 + quad * 4 + r][wh] = s[mi][r];
    }
    __syncthreads();

#pragma unroll
    for (int mi = 0; mi < 4; ++mi)
#pragma unroll
        for (int r = 0; r < 4; ++r) {
            int rl = wm + mi * 16 + quad * 4 + r;
            int row = row0 + rl;
            if (row < M) {
                float rstd = rsqrtf((redS[rl][0] + redS[rl][1]) * (1.f / 128.f) + 1e-5f);
#pragma unroll
                for (int ni = 0; ni < 4; ++ni) {
                    int col = wn + ni * 16 + cl;
                    float d = acc[mi][ni][r] + bv[ni] - mean[mi][r];
                    out[(size_t)row * 128 + col] = fmaf(d * rstd, gv[ni], bev[ni]);
                }
            }
        }
}

// ---------------- edge score kernel (eaperm staging, 512 thr) ----------------
// Per block: 128 CSR-ordered edges, 8 waves.
// Phase 1: ee[128x128] = eaperm_tile @ WeT^T via MFMA, fragments DIRECT from
//          global (eaperm rows coalesced 1KB/wave; WeT 8KB L1-resident).
// Phase 2: g = leaky(ee + xl[src] + xr[dst]) -> Gs (lane=f: coalesced row reads).
// Phase 3: S[128x16] = g @ attB^T (attB block-diag; Ab/Gs stride 136).
// Phase 4: pe[e,h] = exp(S).
template <int STRIDE>
__global__ __launch_bounds__(512) void k_edge_score(const short* __restrict__ eaperm,
                                                    const short* __restrict__ WeT,
                                                    const short* __restrict__ attB,
                                                    const int2* __restrict__ csr_se,
                                                    const int* __restrict__ dstp,
                                                    const short* __restrict__ C,
                                                    float* __restrict__ pe) {
    __shared__ short Gs[128 * 136];
    __shared__ short Ab[16 * 136];
    __shared__ int sS[128], sD[128];
    int t = threadIdx.x;
    int lane = t & 63, wid = t >> 6;          // 8 waves
    int wm2 = (wid & 1) * 64;                 // edge half
    int wn2 = (wid >> 1) * 32;                // f quarter
    int cl = lane & 15, quad = lane >> 4;
    long e0 = (long)blockIdx.x * 128;

    if (t < 128) {
        long ep = e0 + t; if (ep >= NE) ep = NE - 1;
        sS[t] = csr_se[ep].x;
        sD[t] = dstp[ep];
    } else if (t < 384) {
        int u = t - 128;                      // 0..255 -> 16 rows x 16 chunks of 8 shorts
        int rr = u >> 4, cc = (u & 15) * 8;
        *(short8*)&Ab[rr * 136 + cc] = *(const short8*)&attB[rr * 128 + cc];
    }

    // ---- phase 1: fragments direct from global, 8 MFMAs ----
    short8 a[4], b[2];
#pragma unroll
    for (int mi = 0; mi < 4; ++mi) {
        long e = e0 + wm2 + mi * 16 + cl; if (e >= NE) e = NE - 1;
        a[mi] = *(const short8*)&eaperm[e * 32 + quad * 8];
    }
#pragma unroll
    for (int ni = 0; ni < 2; ++ni)
        b[ni] = *(const short8*)&WeT[(size_t)(wn2 + ni * 16 + cl) * 32 + quad * 8];

    f32x4 acc[4][2];
#pragma unroll
    for (int i = 0; i < 4; ++i) { acc[i][0] = (f32x4)0.f; acc[i][1] = (f32x4)0.f; }
#pragma unroll
    for (int mi = 0; mi < 4; ++mi)
#pragma unroll
        for (int ni = 0; ni < 2; ++ni)
            acc[mi][ni] = __builtin_amdgcn_mfma_f32_16x16x32_bf16(a[mi], b[ni], acc[mi][ni], 0, 0, 0);
    __syncthreads();   // sS/sD/Ab ready

    // ---- phase 2: g = leaky(ee + xl + xr) -> Gs (coalesced: lanes = consecutive f) ----
#pragma unroll
    for (int mi = 0; mi < 4; ++mi) {
#pragma unroll
        for (int r = 0; r < 4; ++r) {
            int eloc = wm2 + mi * 16 + quad * 4 + r;
            const short* xlr = C + (size_t)sS[eloc] * STRIDE;
            const short* xrr = C + (size_t)sD[eloc] * STRIDE + 128;
            int f0 = wn2 + cl, f1 = wn2 + 16 + cl;
            float xl0 = bf2f(xlr[f0]), xr0 = bf2f(xrr[f0]);
            float xl1 = bf2f(xlr[f1]), xr1 = bf2f(xrr[f1]);
            float g0 = acc[mi][0][r] + xl0 + xr0;
            float g1 = acc[mi][1][r] + xl1 + xr1;
            g0 = fmaxf(g0, 0.2f * g0);
            g1 = fmaxf(g1, 0.2f * g1);
            Gs[eloc * 136 + f0] = f2bf(g0);
            Gs[eloc * 136 + f1] = f2bf(g1);
        }
    }
    __syncthreads();

    // ---- phase 3: scores = g @ attB^T (16 edges per wave, 4 MFMAs) ----
    f32x4 sacc = (f32x4)0.f;
    int em0 = wid * 16;
#pragma unroll
    for (int ks = 0; ks < 4; ++ks) {
        short8 ag = *(const short8*)&Gs[(em0 + cl) * 136 + ks * 32 + quad * 8];
        short8 bg = *(const short8*)&Ab[cl * 136 + ks * 32 + quad * 8];
        sacc = __builtin_amdgcn_mfma_f32_16x16x32_bf16(ag, bg, sacc, 0, 0, 0);
    }

    // ---- phase 4: exp + store (D layout: col=cl (head), row=quad*4+r (edge)) ----
    if (cl < 4) {
#pragma unroll
        for (int r = 0; r < 4; ++r) {
            long epos = e0 + em0 + quad * 4 + r;
            if (epos < NE) pe[epos * 4 + cl] = __expf(sacc[r]);
        }
    }
}

// ---------------- slim softmax-aggregate + epilogue (4-edge ILP) ----------------
// ONE WAVE PER 2-NODE CHUNK (grid 6250 x 4 waves). Per iteration: 4 edges in
// flight — next-4 csr/pe prefetch overlaps current-4 xl gathers + FMAs.
template <int STRIDE>
__global__ __launch_bounds__(256) void k_fused_agg(const int* __restrict__ off,
                                                   const int2* __restrict__ csr_se,
                                                   const float* __restrict__ pe,
                                                   const short* __restrict__ C,
                                                   const short* __restrict__ resid, int rstride,
                                                   const float* __restrict__ bias,
                                                   const float* __restrict__ gamma,
                                                   const float* __restrict__ beta,
                                                   short* __restrict__ outb) {
    int t = threadIdx.x;
    int w = t >> 6, l = t & 63;
    int f0 = (l >> 4) * 32 + (l & 15) * 2;   // even feature; f1 = f0+1 (same head)
    int fp = f0 >> 1;
    int hd = l >> 4;                          // head index

    float2 bs2 = ((const float2*)bias)[fp];
    float2 gv = ((const float2*)gamma)[fp];
    float2 bev = ((const float2*)beta)[fp];

    int n0 = (blockIdx.x * 4 + w) * 2;
    int nend = n0 + 2; if (nend > NN) nend = NN;

    for (int i = n0; i < nend; ++i) {
        unsigned rp = *(const unsigned*)&resid[(size_t)i * rstride + f0];  // early issue
        int b0 = off[i], b1 = off[i + 1];

        float lr[4] = {0.f, 0.f, 0.f, 0.f};
        float a0[4] = {0.f, 0.f, 0.f, 0.f};
        float a1[4] = {0.f, 0.f, 0.f, 0.f};
        int pos = b0;
        int sC[4] = {0, 0, 0, 0};
        float pC[4] = {0.f, 0.f, 0.f, 0.f};
        bool have = (pos + 4 <= b1);
        if (have) {
#pragma unroll
            for (int j = 0; j < 4; ++j) {
                int2 se = csr_se[pos + j];
                sC[j] = se.x;
                pC[j] = pe[(size_t)(pos + j) * 4 + hd];
            }
        }
        while (have) {
            bool haven = (pos + 8 <= b1);
            int nS[4] = {0, 0, 0, 0};
            float nP[4] = {0.f, 0.f, 0.f, 0.f};
            if (haven) {
#pragma unroll
                for (int j = 0; j < 4; ++j) {
                    int2 se = csr_se[pos + 4 + j];
                    nS[j] = se.x;
                    nP[j] = pe[(size_t)(pos + 4 + j) * 4 + hd];
                }
            }
            unsigned xl[4];
#pragma unroll
            for (int j = 0; j < 4; ++j)
                xl[j] = *(const unsigned*)&C[(size_t)sC[j] * STRIDE + f0];
#pragma unroll
            for (int j = 0; j < 4; ++j) {
                lr[j] += pC[j];
                a0[j] = fmaf(pC[j], bflo(xl[j]), a0[j]);
                a1[j] = fmaf(pC[j], bfhi(xl[j]), a1[j]);
            }
            pos += 4;
#pragma unroll
            for (int j = 0; j < 4; ++j) { sC[j] = nS[j]; pC[j] = nP[j]; }
            have = haven;
        }
        for (; pos < b1; ++pos) {             // tail 0..3 edges
            int2 se = csr_se[pos];
            float p1 = pe[(size_t)pos * 4 + hd];
            unsigned xlv = *(const unsigned*)&C[(size_t)se.x * STRIDE + f0];
            lr[0] += p1;
            a0[0] = fmaf(p1, bflo(xlv), a0[0]);
            a1[0] = fmaf(p1, bfhi(xlv), a1[0]);
        }
        float l_run = (lr[0] + lr[1]) + (lr[2] + lr[3]);
        float acc0 = (a0[0] + a0[1]) + (a0[2] + a0[3]);
        float acc1 = (a1[0] + a1[1]) + (a1[2] + a1[3]);

        float inv = 1.f / (l_run + 1e-16f);
        float o0 = fmaf(acc0, inv, bs2.x);
        float o1 = fmaf(acc1, inv, bs2.y);
        o0 = o0 > 0.f ? o0 : (__expf(o0) - 1.f);            // ELU
        o1 = o1 > 0.f ? o1 : (__expf(o1) - 1.f);
        float v0 = o0 + bflo(rp), v1 = o1 + bfhi(rp);       // + residual
        // in-wave LayerNorm over 128 features (2 per lane)
        float s = v0 + v1;
#pragma unroll
        for (int o = 32; o > 0; o >>= 1) s += __shfl_xor(s, o, 64);
        float mean = s * (1.f / 128.f);
        float d0 = v0 - mean, d1 = v1 - mean;
        float q = fmaf(d0, d0, d1 * d1);
#pragma unroll
        for (int o = 32; o > 0; o >>= 1) q += __shfl_xor(q, o, 64);
        float rstd = rsqrtf(q * (1.f / 128.f) + 1e-5f);
        float r0 = fmaf(d0 * rstd, gv.x, bev.x);
        float r1 = fmaf(d1 * rstd, gv.y, bev.y);
        unsigned op = (unsigned)(unsigned short)f2bf(r0) |
                      (((unsigned)(unsigned short)f2bf(r1)) << 16);
        *(unsigned*)&outb[(size_t)i * 128 + f0] = op;
    }
}

extern "C" void kernel_launch(void* const* d_in, const int* in_sizes, int n_in,
                              void* d_out, int out_size, void* d_ws, size_t ws_size,
                              hipStream_t stream) {
    (void)in_sizes; (void)n_in; (void)out_size; (void)ws_size;
    const float* x     = (const float*)d_in[0];
    const float* ea    = (const float*)d_in[1];
    const float* Wl1   = (const float*)d_in[2];
    const float* bl1   = (const float*)d_in[3];
    const float* Wr1   = (const float*)d_in[4];
    const float* br1   = (const float*)d_in[5];
    const float* We1   = (const float*)d_in[6];
    const float* att1  = (const float*)d_in[7];
    const float* bias1 = (const float*)d_in[8];
    const float* Wl2   = (const float*)d_in[9];
    const float* bl2   = (const float*)d_in[10];
    const float* Wr2   = (const float*)d_in[11];
    const float* br2   = (const float*)d_in[12];
    const float* We2   = (const float*)d_in[13];
    const float* att2  = (const float*)d_in[14];
    const float* bias2 = (const float*)d_in[15];
    const float* Wres  = (const float*)d_in[16];
    const float* bres  = (const float*)d_in[17];
    const float* Wout  = (const float*)d_in[18];
    const float* bout  = (const float*)d_in[19];
    const float* g1    = (const float*)d_in[20];
    const float* bn1   = (const float*)d_in[21];
    const float* g2    = (const float*)d_in[22];
    const float* bn2   = (const float*)d_in[23];
    const float* go    = (const float*)d_in[24];
    const float* bo    = (const float*)d_in[25];
    const int*   ei    = (const int*)d_in[26];
    const int* srcv = ei;
    const int* dstv = ei + NE;
    float* outp = (float*)d_out;

    char* p = (char*)d_ws;
    auto carve = [&](size_t bytes) {
        char* r = p;
        p += (bytes + 255) & ~(size_t)255;
        return r;
    };
    short* xb    = (short*)carve((size_t)NN * KP1 * 2);
    short* Wt1   = (short*)carve((size_t)384 * KP1 * 2);
    short* Wt2   = (short*)carve((size_t)256 * 128 * 2);
    short* Wt3   = (short*)carve((size_t)128 * 128 * 2);
    short* WeT1  = (short*)carve((size_t)128 * 32 * 2);
    short* WeT2  = (short*)carve((size_t)128 * 32 * 2);
    short* attB1 = (short*)carve((size_t)16 * 128 * 2);
    short* attB2 = (short*)carve((size_t)16 * 128 * 2);
    float* bcat1 = (float*)carve(384 * 4);
    float* bcat2 = (float*)carve(256 * 4);
    short* C1    = (short*)carve((size_t)NN * 384 * 2);   // bf16 [xl|xr|res]
    short* h1b   = (short*)carve((size_t)NN * 128 * 2);
    short* h2b   = (short*)carve((size_t)NN * 128 * 2);
    int* off     = (int*)carve((size_t)(NN + 1) * 4);
    int* cur     = (int*)carve((size_t)NN * 4);
    int* bsum    = (int*)carve(256 * 4);
    int2* csr_se = (int2*)carve((size_t)NE * 8);          // {src, edge_id} per CSR position
    int* dstp    = (int*)carve((size_t)NE * 4);           // filled contiguously from off
    short* eaperm = (short*)carve((size_t)NE * 32 * 2);   // 32 MB, CSR-ordered bf16 ea (K pad 32)
    float* pe    = (float*)carve((size_t)NE * 4 * 4);     // 8 MB, exp(score) per edge x head

    short* C2 = C1;                                  // stride 256, reuse after layer 1

    const int NB = (NN + 255) / 256;                 // 196

    // ---- CSR build + input prep (count fused into vectorized cvt_x) ----
    hipMemsetAsync(cur, 0, (size_t)NN * 4, stream);
    k_cvt_x_count<<<((size_t)NN * CVT_CH + 255) / 256, 256, 0, stream>>>(x, xb, dstv, cur);
    k_scan1<<<NB, 256, 0, stream>>>(cur, off, bsum);
    k_scan2<<<1, 256, 0, stream>>>(bsum, NB);
    k_scan3c<<<(NN + 256) / 256, 256, 0, stream>>>(off, bsum, cur);
    k_scatter<<<(NE + 255) / 256, 256, 0, stream>>>(srcv, dstv, cur, csr_se);

    // ---- prep ----
    int prep_total = 384 * KP1 + 256 * 128 + 128 * 128 + 384 + 256 + 2 * 128 * 32 + 2 * 16 * 128;
    k_prep_w<<<(prep_total + 255) / 256, 256, 0, stream>>>(Wl1, Wr1, Wres, Wl2, Wr2, Wout,
                                                           bl1, br1, bres, bl2, br2,
                                                           We1, We2, att1, att2,
                                                           Wt1, Wt2, Wt3, bcat1, bcat2,
                                                           WeT1, WeT2, attB1, attB2);
    k_gather_ea<<<(NE + 255) / 256, 256, 0, stream>>>(csr_se, ea, eaperm, off, dstp);

    int mb  = (NN + 127) / 128;                      // 391
    int ebk = (NE + 127) / 128;                      // 3907
    int gagg = NN / 8;                               // 6250 blocks (4 waves x 2 nodes)

    // ---- layer 1 ----
    k_mfma_gemm<true><<<dim3(mb, 3), 256, 0, stream>>>(xb, Wt1, bcat1, nullptr, C1, NN, KP1, 384);
    k_edge_score<384><<<ebk, 512, 0, stream>>>(eaperm, WeT1, attB1, csr_se, dstp, C1, pe);
    k_fused_agg<384><<<gagg, 256, 0, stream>>>(off, csr_se, pe, C1,
                                               C1 + 256, 384, bias1, g1, bn1, h1b);
    // ---- layer 2 ----
    k_mfma_gemm<true><<<dim3(mb, 2), 256, 0, stream>>>(h1b, Wt2, bcat2, nullptr, C2, NN, 128, 256);
    k_edge_score<256><<<ebk, 512, 0, stream>>>(eaperm, WeT2, attB2, csr_se, dstp, C2, pe);
    k_fused_agg<256><<<gagg, 256, 0, stream>>>(off, csr_se, pe, C2,
                                               h1b, 128, bias2, g2, bn2, h2b);
    // ---- output: GEMM + fused LN ----
    k_gemm_ln<<<mb, 256, 0, stream>>>(h2b, Wt3, bout, go, bo, outp, NN);
}